// Round 3
// baseline (235.043 us; speedup 1.0000x reference)
//
#include <hip/hip_runtime.h>

typedef __attribute__((ext_vector_type(8))) _Float16 half8;
typedef __attribute__((ext_vector_type(4))) _Float16 half4;
typedef __attribute__((ext_vector_type(4))) float floatx4;

// ---------------- kW: fp32 -> fp16 weight planes ----------------
// w1 is reordered g-major: w1fr[n][g*136 + j] = w1[n][kold(g,j)], j<132 valid, 132..135 zero.
//   j<36  : kold = g*36 + j                (x1 block)
//   j<84  : kold = 576 + g*48 + (j-36)     (x2 block)
//   j<132 : kold = 1344 + g*48 + (j-84)    (x3 block)
// row stride 2176 halves -> every (n, g, 16B chunk) is 16B-aligned.
__global__ __launch_bounds__(256) void kW(const float* __restrict__ w1,
                                          const float* __restrict__ w2,
                                          const float* __restrict__ w3,
                                          _Float16* __restrict__ w1fr,
                                          _Float16* __restrict__ w2f,
                                          _Float16* __restrict__ w3f) {
  int i = blockIdx.x * 256 + threadIdx.x;
  if (i < 208896) {                       // 96 * 2176
    int n = i / 2176, kn = i - n * 2176;
    int g = kn / 136, j = kn - g * 136;
    _Float16 v = (_Float16)0.f;
    if (j < 132) {
      int kold = (j < 36) ? (g * 36 + j)
               : (j < 84) ? (576 + g * 48 + (j - 36))
                          : (1344 + g * 48 + (j - 84));
      v = (_Float16)w1[n * 2112 + kold];
    }
    w1fr[i] = v;
  } else {
    int i2 = i - 208896;
    if (i2 < 9216) w2f[i2] = (_Float16)w2[i2];
    else if (i2 < 18432) w3f[i2 - 9216] = (_Float16)w3[i2 - 9216];
  }
}

// ---------------- kFused: unfold-gather + descriptor max + GEMM1 (split-K over g) -------
// grid = 1792 = (gp 8) x (h 56) x (b 4); 256 threads. Block handles g = 2*gp, 2*gp+1,
// accumulating K=2*132 into acc; writes one pacc slice [gp][12544][96] fp16.
// A-tile built in LDS [64 rows(w) x 168 halves(k)], pads zero; B read direct from w1fr (L2).
__global__ __launch_bounds__(256) void kFused(const float* __restrict__ x,
                                              const _Float16* __restrict__ w1fr,
                                              _Float16* __restrict__ pacc) {
  int bid = blockIdx.x;
  int gp = bid & 7;
  int rest = bid >> 3;
  int h = rest % 56;
  int b = rest / 56;

  // xb row stride = 72 halves (144 B). chunk c (8 halves) stored at c ^ (kk&7).
  __shared__ __align__(16) _Float16 xb[144 * 72];     // 20736 B
  __shared__ __align__(16) _Float16 Abuf[64 * 168];   // 21504 B, A[w][j]
  __shared__ __align__(16) int tOf[132][4];           // enc = row*144 | key (key=kk&7)

  const int t = threadIdx.x;
  const int wv = t >> 6, lane = t & 63, quad = lane >> 4, lr = lane & 15;

  // ---- tap-offset table (g-independent) ----
  if (t < 132) {
    int dl = t;
    int r0, r1, r2, r3;
    if (dl < 36) {                       // x1: max over 4 sub-channels
      int a3 = dl / 9, rem = dl % 9, k1 = rem / 3, k2 = rem % 3;
      int br = (k2 * 3 + k1) * 16 + a3;
      r0 = br; r1 = br + 4; r2 = br + 8; r3 = br + 12;
    } else if (dl < 84) {                // x2: max over k1
      int u = dl - 36, gc = u / 3, k2 = u % 3;
      r0 = (k2 * 3 + 0) * 16 + gc;
      r1 = (k2 * 3 + 1) * 16 + gc;
      r2 = (k2 * 3 + 2) * 16 + gc;
      r3 = r0;
    } else {                             // x3: max over k2
      int u = dl - 84, gc = u / 3, k1 = u % 3;
      r0 = (0 + k1) * 16 + gc;
      r1 = (3 + k1) * 16 + gc;
      r2 = (6 + k1) * 16 + gc;
      r3 = r0;
    }
    tOf[dl][0] = r0 * 144 + ((r0 >> 4) & 7);
    tOf[dl][1] = r1 * 144 + ((r1 >> 4) & 7);
    tOf[dl][2] = r2 * 144 + ((r2 >> 4) & 7);
    tOf[dl][3] = r3 * 144 + ((r3 >> 4) & 7);
  }

  // ---- zero Abuf once (valid region rewritten every g-iteration; pads stay 0) ----
#pragma unroll
  for (int i = 0; i < 6; ++i) {
    int idx = t + i * 256;
    if (idx < 1344) *(half8*)(Abuf + idx * 8) = (half8)(_Float16)0.f;
  }
  __syncthreads();

  floatx4 acc[6];
#pragma unroll
  for (int j = 0; j < 6; ++j) acc[j] = {0.f, 0.f, 0.f, 0.f};

  for (int gi = 0; gi < 2; ++gi) {
    const int g = gp * 2 + gi;

    // ---- fill xb: 144 rows x 56 cols (per-k2 shift folded), float4 loads ----
    {
      const long xp = ((long)b * 256 + g * 16) * 3136;
#pragma unroll
      for (int i = 0; i < 8; ++i) {
        int idx = t + i * 256;
        if (idx < 2016) {
          int r = idx / 14, c4 = idx - r * 14;
          int kk = r >> 4, ch = r & 15;
          int k2 = kk / 3, k1 = kk - 3 * k2;
          int t2 = k2 * 56 + h;
          int q3 = t2 / 3;
          int gr = q3 + k1 - 1;
          int s = t2 - q3 * 3;            // column shift for this row's k2
          int col0 = c4 * 4;
          half4 hv;
          if (gr >= 0 && gr < 56) {
            long rb = xp + (long)ch * 3136 + (long)gr * 56 + (s - 1) + col0;
            bool interior = (col0 > 0 || s > 0) && (c4 < 13 || s < 2);
            if (interior) {
              float fv[4];
              __builtin_memcpy(fv, x + rb, 16);
              hv[0] = (_Float16)fv[0]; hv[1] = (_Float16)fv[1];
              hv[2] = (_Float16)fv[2]; hv[3] = (_Float16)fv[3];
            } else {
#pragma unroll
              for (int e = 0; e < 4; ++e) {
                int cg = col0 + e + s - 1;
                float v = 0.f;
                if ((unsigned)cg < 56u) v = x[rb + e];
                hv[e] = (_Float16)v;
              }
            }
          } else {
#pragma unroll
            for (int e = 0; e < 4; ++e) hv[e] = (_Float16)0.f;
          }
          int key = kk & 7;
          int chunk = (c4 >> 1) ^ key;
          *(half4*)((char*)xb + r * 144 + chunk * 16 + (c4 & 1) * 8) = hv;
        }
      }
    }
    __syncthreads();

    // ---- build A: unit (pc 0..6, dl 0..131); half8 along w -> 8 ds_write_u16 ----
    // write banks: dl varies across lanes -> conflict-free.
#pragma unroll
    for (int i = 0; i < 4; ++i) {
      int idx = t + i * 256;
      if (idx < 924) {
        int pc = idx / 132, dl = idx - pc * 132;
        const int4 of = *(const int4*)tOf[dl];
        const char* xbb = (const char*)xb;
        half8 v0 = *(const half8*)(xbb + (of.x & ~15) + ((pc ^ (of.x & 15)) << 4));
        half8 v1 = *(const half8*)(xbb + (of.y & ~15) + ((pc ^ (of.y & 15)) << 4));
        half8 v2 = *(const half8*)(xbb + (of.z & ~15) + ((pc ^ (of.z & 15)) << 4));
        half8 v3 = *(const half8*)(xbb + (of.w & ~15) + ((pc ^ (of.w & 15)) << 4));
#pragma unroll
        for (int e = 0; e < 8; ++e) {
          _Float16 a = v0[e] > v1[e] ? v0[e] : v1[e];
          _Float16 c = v2[e] > v3[e] ? v2[e] : v3[e];
          Abuf[(pc * 8 + e) * 168 + dl] = a > c ? a : c;
        }
      }
    }
    __syncthreads();

    // ---- MFMA: K = 160 (132 valid + zero pad); B direct from w1fr (L2-hot) ----
    const _Float16* wb = w1fr + g * 136;
#pragma unroll
    for (int ks = 0; ks < 5; ++ks) {
      half8 af = *(const half8*)(Abuf + (wv * 16 + lr) * 168 + ks * 32 + quad * 8);
#pragma unroll
      for (int j = 0; j < 6; ++j) {
        half8 bf = *(const half8*)(wb + (long)(j * 16 + lr) * 2176 + ks * 32 + quad * 8);
        acc[j] = __builtin_amdgcn_mfma_f32_16x16x32_f16(af, bf, acc[j], 0, 0, 0);
      }
    }
    if (gi == 0) __syncthreads();        // done reading xb/Abuf before overwrite
  }

  // ---- store partial slice: pacc[gp][m][n], m = (b*56+h)*56 + w, rows w<56 ----
  _Float16* pp = pacc + ((long)gp * 12544 + (long)(b * 56 + h) * 56) * 96;
#pragma unroll
  for (int j = 0; j < 6; ++j)
#pragma unroll
    for (int r = 0; r < 4; ++r) {
      int row = wv * 16 + quad * 4 + r;
      if (row < 56) pp[row * 96 + j * 16 + lr] = (_Float16)acc[j][r];
    }
}

// ---------------- kRed: sum 8 split-K partials + BN + ReLU -> y fp16 [12544, 96] -------
// 1176 blocks x 256 threads x 4 elements = 1,204,224 = 196*6144 exactly.
__global__ __launch_bounds__(256) void kRed(
    const _Float16* __restrict__ pacc,
    const float* __restrict__ gamma, const float* __restrict__ beta,
    const float* __restrict__ mean, const float* __restrict__ var,
    _Float16* __restrict__ yred) {
  __shared__ float invv[96], biasv[96];
  int t = threadIdx.x;
  if (t < 96) {
    float iv = gamma[t] * rsqrtf(var[t] + 1e-5f);
    invv[t] = iv; biasv[t] = beta[t] - mean[t] * iv;
  }
  __syncthreads();
  long base = (long)blockIdx.x * 1024 + t * 4;
  float s0 = 0.f, s1 = 0.f, s2 = 0.f, s3 = 0.f;
#pragma unroll
  for (int ck = 0; ck < 8; ++ck) {
    half4 v = *(const half4*)(pacc + (long)ck * 1204224 + base);
    s0 += (float)v.x; s1 += (float)v.y; s2 += (float)v.z; s3 += (float)v.w;
  }
  int n0 = (int)(base % 96);   // 4-aligned, 96%4==0 -> no row crossing
  half4 o;
  o.x = (_Float16)fmaxf(s0 * invv[n0 + 0] + biasv[n0 + 0], 0.f);
  o.y = (_Float16)fmaxf(s1 * invv[n0 + 1] + biasv[n0 + 1], 0.f);
  o.z = (_Float16)fmaxf(s2 * invv[n0 + 2] + biasv[n0 + 2], 0.f);
  o.w = (_Float16)fmaxf(s3 * invv[n0 + 3] + biasv[n0 + 3], 0.f);
  *(half4*)(yred + base) = o;
}

// ---------------- kGemm2: y tile -> GEMM2 (w2,w3) -> softmax -> wt fp16 ----
__global__ __launch_bounds__(256) void kGemm2(
    const _Float16* __restrict__ yred,
    const _Float16* __restrict__ w2f, const _Float16* __restrict__ w3f,
    const float* __restrict__ b2, const float* __restrict__ b3,
    _Float16* __restrict__ wtg) {
  __shared__ __align__(16) char smem[49152];
  _Float16* ytF = (_Float16*)smem;        // [0, 13312): 64*104 fp16 (dead after MFMA loop)
  float* wal = (float*)smem;              // [0, 24576): 64*96 f32  (after ytF dead)
  float* wbl = wal + 6144;                // [24576, 49152): 64*96 f32

  const int t = threadIdx.x;
  const int wv = t >> 6, lane = t & 63, quad = lane >> 4, lr = lane & 15;
  const int mt = blockIdx.x;
  const long mblk = (long)mt * 64;

  // load y tile (coalesced fp16) -> ytF [64][104]
  {
    const _Float16* yb = yred + mblk * 96;
#pragma unroll
    for (int i = 0; i < 24; ++i) {
      int idx = t + i * 256;
      int m = idx / 96, n = idx - m * 96;
      ytF[m * 104 + n] = yb[idx];
    }
  }
  __syncthreads();

  floatx4 acc2a[6], acc2b[6];
#pragma unroll
  for (int j = 0; j < 6; ++j) { acc2a[j] = {0.f,0.f,0.f,0.f}; acc2b[j] = {0.f,0.f,0.f,0.f}; }
#pragma unroll
  for (int ks = 0; ks < 3; ++ks) {
    half8 af = *(const half8*)(ytF + (wv * 16 + lr) * 104 + ks * 32 + quad * 8);
#pragma unroll
    for (int j = 0; j < 6; ++j) {
      int wo = (j * 16 + lr) * 96 + ks * 32 + quad * 8;
      half8 b2v = *(const half8*)(w2f + wo);
      half8 b3v = *(const half8*)(w3f + wo);
      acc2a[j] = __builtin_amdgcn_mfma_f32_16x16x32_f16(af, b2v, acc2a[j], 0, 0, 0);
      acc2b[j] = __builtin_amdgcn_mfma_f32_16x16x32_f16(af, b3v, acc2b[j], 0, 0, 0);
    }
  }
  __syncthreads();   // ytF dead; smem becomes wal/wbl

#pragma unroll
  for (int j = 0; j < 6; ++j) {
    int n = j * 16 + lr;
    float bb2 = b2[n], bb3 = b3[n];
#pragma unroll
    for (int r = 0; r < 4; ++r) {
      int m = wv * 16 + quad * 4 + r;
      wal[m * 96 + n] = acc2a[j][r] + bb2;
      wbl[m * 96 + n] = acc2b[j][r] + bb3;
    }
  }
  __syncthreads();

  for (int it = 0; it < 16; ++it) {
    int u = t + it * 256;
    int m = u >> 6, rest = u & 63;
    int g = rest >> 2, ns = rest & 3;
    int ns1 = ns >> 1, ns2 = ns & 1;
    float la[3], lb[3];
#pragma unroll
    for (int k = 0; k < 3; ++k) {
      la[k] = wal[m * 96 + (g * 3 + k) * 2 + ns1];
      lb[k] = wbl[m * 96 + (g * 3 + k) * 2 + ns2];
    }
    float lg[9], mx = -1e30f;
#pragma unroll
    for (int k1 = 0; k1 < 3; ++k1)
#pragma unroll
      for (int k2 = 0; k2 < 3; ++k2) {
        float v = la[k1] * lb[k2];
        lg[k1 * 3 + k2] = v;
        mx = v > mx ? v : mx;
      }
    float s = 0.f;
#pragma unroll
    for (int k = 0; k < 9; ++k) { lg[k] = __expf(lg[k] - mx); s += lg[k]; }
    float sc = 1.f / (9.f * s);
    _Float16* dst = wtg + (mblk + m) * 576 + g * 36 + ns * 9;
#pragma unroll
    for (int k = 0; k < 9; ++k) dst[k] = (_Float16)(lg[k] * sc);
  }
}

// ---------------- kApply: x + wt -> out ----------
// block = (b, h', wh(2), g(16)): 7168 blocks, 256 threads; 16 channels, 28 w-positions.
__global__ __launch_bounds__(256) void kApply(const float* __restrict__ x,
                                              const _Float16* __restrict__ wt,
                                              float* __restrict__ out) {
  int bid = blockIdx.x;
  int g = bid & 15;
  int wh = (bid >> 4) & 1;
  int h = (bid >> 5) % 56;
  int b = bid / 1792;
  int wbase = wh * 28, cbase = g * 16;

  __shared__ _Float16 xr[9 * 16 * 30];       // [(k2*3+k1)*480 + cl*30 + wc]
  __shared__ __align__(16) float wtb[28 * 36]; // [p*36 + (k1*3+k2)*4 + ns]
  __shared__ float ob[32 * 57];              // [(cl*2+ns1)*57 + p*2+ns2]

  int t = threadIdx.x;

  // fill xr: 144 rows x 30 cols; fully-batched loads
  {
    int wc = t & 31;
    int r0 = t >> 5;                    // 0..7
    int wr = wbase + wc - 1;
    bool wok = (wc < 30) & (wr >= 0) & (wr < 56);
    const long xb0 = ((long)b * 256 + cbase) * 3136;
    float vals[18];
#pragma unroll
    for (int i = 0; i < 18; ++i) {
      int row = r0 + i * 8;             // 0..143
      int kk = row >> 4, cl = row & 15;
      int k2 = kk / 3, k1 = kk - 3 * k2;
      int gr = (k2 * 56 + h) / 3 + k1 - 1;
      float v = 0.f;
      if (wok && gr >= 0 && gr < 56)
        v = x[xb0 + (long)cl * 3136 + gr * 56 + wr];
      vals[i] = v;
    }
#pragma unroll
    for (int i = 0; i < 18; ++i) {
      int row = r0 + i * 8;
      if (wc < 30) xr[row * 30 + wc] = (_Float16)vals[i];
    }
  }
  // wt -> wtb: wtb[p*36 + kk*4 + ns] = wt[(m0+p)*576 + g*36 + ns*9 + kk]
  {
    long m0 = ((long)(b * 56 + h)) * 56 + wbase;
    float vals[4];
#pragma unroll
    for (int i = 0; i < 4; ++i) {
      int idx = t + i * 256;
      if (idx < 1008) {
        int p = idx / 36, r36 = idx - p * 36;
        int kk = r36 >> 2, ns = r36 & 3;
        vals[i] = (float)wt[(m0 + p) * 576 + g * 36 + ns * 9 + kk];
      }
    }
#pragma unroll
    for (int i = 0; i < 4; ++i) {
      int idx = t + i * 256;
      if (idx < 1008) wtb[idx] = vals[i];
    }
  }
  __syncthreads();

  // compute: thread owns (cl, p); 4 ns accumulators; float4 weight reads
  {
    int j2r[3];
#pragma unroll
    for (int k2 = 0; k2 < 3; ++k2) j2r[k2] = (k2 * 56 + h) % 3;
#pragma unroll
    for (int i = 0; i < 2; ++i) {
      int idx = i * 256 + t;
      int cl = idx & 15;
      int p = idx >> 4;                 // 0..31
      if (p < 28) {
        float a0 = 0.f, a1 = 0.f, a2 = 0.f, a3 = 0.f;
#pragma unroll
        for (int k1 = 0; k1 < 3; ++k1)
#pragma unroll
          for (int k2 = 0; k2 < 3; ++k2) {
            float xv = (float)xr[(k2 * 3 + k1) * 480 + cl * 30 + p + j2r[k2]];
            float4 wv = *(const float4*)&wtb[p * 36 + (k1 * 3 + k2) * 4];
            a0 += xv * wv.x; a1 += xv * wv.y; a2 += xv * wv.z; a3 += xv * wv.w;
          }
        int ob0 = cl * 114 + p * 2;
        ob[ob0] = a0;
        ob[ob0 + 1] = a1;
        ob[ob0 + 57] = a2;
        ob[ob0 + 58] = a3;
      }
    }
  }
  __syncthreads();

  // writeout: 32 rows x 56 cols, coalesced
  {
    int wo = t & 63;
    int r0 = t >> 6;                    // 0..3
    const long obase = (((long)b * 256 + cbase) * 112 + 2 * h) * 112 + wh * 56;
#pragma unroll
    for (int i = 0; i < 8; ++i) {
      int row = r0 + i * 4;             // 0..31
      if (wo < 56) {
        int cli = row >> 1, n1 = row & 1;
        out[obase + cli * 12544 + n1 * 112 + wo] = ob[row * 57 + wo];
      }
    }
  }
}

extern "C" void kernel_launch(void* const* d_in, const int* in_sizes, int n_in,
                              void* d_out, int out_size, void* d_ws, size_t ws_size,
                              hipStream_t stream) {
  const float* x = (const float*)d_in[0];
  const float* w1 = (const float*)d_in[1];
  const float* gamma = (const float*)d_in[2];
  const float* beta = (const float*)d_in[3];
  const float* mean = (const float*)d_in[4];
  const float* var = (const float*)d_in[5];
  const float* w2 = (const float*)d_in[6];
  const float* b2 = (const float*)d_in[7];
  const float* w3 = (const float*)d_in[8];
  const float* b3 = (const float*)d_in[9];
  float* out = (float*)d_out;

  // workspace layout (bytes):
  //   (unused legacy region) [0, 405504)
  //   w2f fp16:   [405504, 423936)
  //   w3f fp16:   [423936, 442368)
  //   wtg fp16:   [442368, 14893056)
  //   w1fr fp16:  [14893056, 15310848)   (96 x 2176, g-major reorder, 16B-aligned slices)
  //   pacc fp16:  [67878912, 87146496)   (8 split-K slices)
  //   yred fp16:  [94371840, 96780288)
  _Float16* w2f = (_Float16*)d_ws + 202752;
  _Float16* w3f = w2f + 9216;
  _Float16* wtg = (_Float16*)((char*)d_ws + 442368);
  _Float16* w1fr = (_Float16*)((char*)d_ws + 14893056);
  _Float16* pacc = (_Float16*)((char*)d_ws + 67878912);
  _Float16* yred = (_Float16*)((char*)d_ws + 94371840);

  hipLaunchKernelGGL(kW, dim3(888), dim3(256), 0, stream, w1, w2, w3, w1fr, w2f, w3f);
  hipLaunchKernelGGL(kFused, dim3(1792), dim3(256), 0, stream, x, w1fr, pacc);
  hipLaunchKernelGGL(kRed, dim3(1176), dim3(256), 0, stream,
                     pacc, gamma, beta, mean, var, yred);
  hipLaunchKernelGGL(kGemm2, dim3(196), dim3(256), 0, stream,
                     yred, w2f, w3f, b2, b3, wtg);
  hipLaunchKernelGGL(kApply, dim3(7168), dim3(256), 0, stream, x, wtg, out);
}

// Round 4
// 187.754 us; speedup vs baseline: 1.2519x; 1.2519x over previous
//
#include <hip/hip_runtime.h>

typedef __attribute__((ext_vector_type(8))) _Float16 half8;
typedef __attribute__((ext_vector_type(4))) _Float16 half4;
typedef __attribute__((ext_vector_type(4))) float floatx4;

// async global->LDS DMA, 16B per lane; lds must be wave-uniform base (+lane*16 implicit)
__device__ inline void gld16(const _Float16* g, _Float16* lds) {
  __builtin_amdgcn_global_load_lds(
      (const __attribute__((address_space(1))) unsigned int*)g,
      (__attribute__((address_space(3))) unsigned int*)lds, 16, 0, 0);
}

// ---------------- kW: fp32 -> fp16 weight planes ----------------
__global__ __launch_bounds__(256) void kW(const float* __restrict__ w1,
                                          const float* __restrict__ w2,
                                          const float* __restrict__ w3,
                                          _Float16* __restrict__ w1f,
                                          _Float16* __restrict__ w2f,
                                          _Float16* __restrict__ w3f) {
  int i = blockIdx.x * 256 + threadIdx.x;
  if (i < 202752) w1f[i] = (_Float16)w1[i];
  else if (i < 211968) w2f[i - 202752] = (_Float16)w2[i - 202752];
  else if (i < 221184) w3f[i - 211968] = (_Float16)w3[i - 211968];
}

// ---------------- kDesc v3: v2 structure at 512 threads (halved serial depth) ----------
// tap(k1,k2) at (h',w') = x[row=(k2*56+h')/3+k1-1, col=w'+(k2*56+h')%3-1], zero-pad.
__global__ __launch_bounds__(512) void kDesc(const float* __restrict__ x,
                                             _Float16* __restrict__ descF) {
  int bid = blockIdx.x;
  int g = bid & 15;
  int h = (bid >> 4) % 56;
  int b = bid / 896;

  // xb row stride = 72 halves (144 B). chunk c (8 halves) stored at c ^ (kk&7).
  __shared__ __align__(16) _Float16 xb[144 * 72];   // 20736 B
  __shared__ __align__(16) int tOf[132][4];         // enc = row*144 | key (key=kk&7)
  __shared__ int tDg[132];

  const int t = threadIdx.x;

  // ---- tap-offset table (132 threads) ----
  if (t < 132) {
    int dl = t;
    int r0, r1, r2, r3, dg;
    if (dl < 36) {                       // x1: max over 4 sub-channels
      int a3 = dl / 9, rem = dl % 9, k1 = rem / 3, k2 = rem % 3;
      int br = (k2 * 3 + k1) * 16 + a3;
      r0 = br; r1 = br + 4; r2 = br + 8; r3 = br + 12;
      dg = g * 36 + dl;
    } else if (dl < 84) {                // x2: max over k1
      int u = dl - 36, gc = u / 3, k2 = u % 3;
      r0 = (k2 * 3 + 0) * 16 + gc;
      r1 = (k2 * 3 + 1) * 16 + gc;
      r2 = (k2 * 3 + 2) * 16 + gc;
      r3 = r0;
      dg = 576 + g * 48 + u;
    } else {                             // x3: max over k2
      int u = dl - 84, gc = u / 3, k1 = u % 3;
      r0 = (0 + k1) * 16 + gc;
      r1 = (3 + k1) * 16 + gc;
      r2 = (6 + k1) * 16 + gc;
      r3 = r0;
      dg = 1344 + g * 48 + u;
    }
    tOf[dl][0] = r0 * 144 + ((r0 >> 4) & 7);
    tOf[dl][1] = r1 * 144 + ((r1 >> 4) & 7);
    tOf[dl][2] = r2 * 144 + ((r2 >> 4) & 7);
    tOf[dl][3] = r3 * 144 + ((r3 >> 4) & 7);
    tDg[dl] = dg;
  }

  // ---- fill xb: 144 rows x 56 cols (shift folded), float4 loads; 2016 units / 512 ----
  {
    const long xp = ((long)b * 256 + g * 16) * 3136;
#pragma unroll
    for (int i = 0; i < 4; ++i) {
      int idx = t + i * 512;
      if (idx < 2016) {
        int r = idx / 14, c4 = idx - r * 14;
        int kk = r >> 4, ch = r & 15;
        int k2 = kk / 3, k1 = kk - 3 * k2;
        int t2 = k2 * 56 + h;
        int q3 = t2 / 3;
        int gr = q3 + k1 - 1;
        int s = t2 - q3 * 3;              // column shift for this row's k2
        int col0 = c4 * 4;
        half4 hv;
        if (gr >= 0 && gr < 56) {
          long rb = xp + (long)ch * 3136 + (long)gr * 56 + (s - 1) + col0;
          bool interior = (col0 > 0 || s > 0) && (c4 < 13 || s < 2);
          if (interior) {
            float fv[4];
            __builtin_memcpy(fv, x + rb, 16);
            hv[0] = (_Float16)fv[0]; hv[1] = (_Float16)fv[1];
            hv[2] = (_Float16)fv[2]; hv[3] = (_Float16)fv[3];
          } else {
#pragma unroll
            for (int e = 0; e < 4; ++e) {
              int cg = col0 + e + s - 1;   // global x column
              float v = 0.f;
              if ((unsigned)cg < 56u) v = x[rb + e];
              hv[e] = (_Float16)v;
            }
          }
        } else {
#pragma unroll
          for (int e = 0; e < 4; ++e) hv[e] = (_Float16)0.f;
        }
        int key = kk & 7;
        int chunk = (c4 >> 1) ^ key;
        *(half4*)((char*)xb + r * 144 + chunk * 16 + (c4 & 1) * 8) = hv;
      }
    }
  }
  __syncthreads();

  // ---- compute + store: unit = (pc, dl); 924 units / 512 threads ----
  const long m00 = ((long)(b * 56 + h)) * 56;
#pragma unroll
  for (int i = 0; i < 2; ++i) {
    int idx = t + i * 512;
    if (idx < 924) {
      int pc = idx / 132, dl = idx - pc * 132;
      const int4 of = *(const int4*)tOf[dl];
      const char* xbb = (const char*)xb;
      half8 v0 = *(const half8*)(xbb + (of.x & ~15) + ((pc ^ (of.x & 15)) << 4));
      half8 v1 = *(const half8*)(xbb + (of.y & ~15) + ((pc ^ (of.y & 15)) << 4));
      half8 v2 = *(const half8*)(xbb + (of.z & ~15) + ((pc ^ (of.z & 15)) << 4));
      half8 v3 = *(const half8*)(xbb + (of.w & ~15) + ((pc ^ (of.w & 15)) << 4));
      half8 r8;
#pragma unroll
      for (int e = 0; e < 8; ++e) {
        _Float16 a = v0[e] > v1[e] ? v0[e] : v1[e];
        _Float16 c = v2[e] > v3[e] ? v2[e] : v3[e];
        r8[e] = a > c ? a : c;
      }
      _Float16* dp = descF + (m00 + pc * 8) * 2112 + tDg[dl];
#pragma unroll
      for (int e = 0; e < 8; ++e) dp[(long)e * 2112] = r8[e];
    }
  }
}

// ---------------- kGemm1: split-K partial GEMM, LDS-staged via global_load_lds ----------
// grid = 196 Mtiles x 11 K-chunks = 2156 blocks; 256 threads; M=64, N=96, K-chunk=192, BK=32.
__global__ __launch_bounds__(256) void kGemm1(
    const _Float16* __restrict__ descF, const _Float16* __restrict__ w1f,
    _Float16* __restrict__ pacc) {
  __shared__ _Float16 Ab[2][64 * 32];   // [row*32 + c*8]
  __shared__ _Float16 Bb[2][96 * 32];   // [n*32 + c*8]
  const int t = threadIdx.x;
  const int wv = t >> 6, lane = t & 63, quad = lane >> 4, lr = lane & 15;
  const int mt = blockIdx.x / 11, ck = blockIdx.x % 11;
  const long mblk = (long)mt * 64;

  const long agbase = (mblk + (t >> 2)) * 2112 + ck * 192 + (t & 3) * 8;
  const long bg0 = (long)(t >> 2) * 2112 + ck * 192 + (t & 3) * 8;
  const long bg1 = (long)((256 + t) >> 2) * 2112 + ck * 192 + (t & 3) * 8;
  const int wslot = (t >> 6) * 512;     // wave-uniform LDS base (halves)

  floatx4 acc[6];
#pragma unroll
  for (int j = 0; j < 6; ++j) acc[j] = {0.f, 0.f, 0.f, 0.f};

  gld16(descF + agbase, &Ab[0][wslot]);
  gld16(w1f + bg0, &Bb[0][wslot]);
  if (t < 128) gld16(w1f + bg1, &Bb[0][2048 + wslot]);

  int buf = 0;
  for (int kt = 0; kt < 6; ++kt) {
    __syncthreads();
    if (kt < 5) {
      int off = (kt + 1) * 32;
      gld16(descF + agbase + off, &Ab[buf ^ 1][wslot]);
      gld16(w1f + bg0 + off, &Bb[buf ^ 1][wslot]);
      if (t < 128) gld16(w1f + bg1 + off, &Bb[buf ^ 1][2048 + wslot]);
    }
    half8 af = *(const half8*)(&Ab[buf][(wv * 16 + lr) * 32 + quad * 8]);
#pragma unroll
    for (int j = 0; j < 6; ++j) {
      half8 bf = *(const half8*)(&Bb[buf][(j * 16 + lr) * 32 + quad * 8]);
      acc[j] = __builtin_amdgcn_mfma_f32_16x16x32_f16(af, bf, acc[j], 0, 0, 0);
    }
    buf ^= 1;
  }

  _Float16* pp = pacc + (long)(ck * 196 + mt) * 6144;
#pragma unroll
  for (int j = 0; j < 6; ++j)
#pragma unroll
    for (int r = 0; r < 4; ++r)
      pp[(wv * 16 + quad * 4 + r) * 96 + j * 16 + lr] = (_Float16)acc[j][r];
}

// ---------------- kGemm2 v2: reduce(11 pacc)+BN+ReLU -> y tile -> GEMM2 -> softmax ------
// grid = 392 blocks x 256 threads; 32 rows per block; waves = 2(row-half) x 2(col-half).
__global__ __launch_bounds__(256) void kGemm2(
    const _Float16* __restrict__ pacc,
    const float* __restrict__ gamma, const float* __restrict__ beta,
    const float* __restrict__ mean, const float* __restrict__ var,
    const _Float16* __restrict__ w2f, const _Float16* __restrict__ w3f,
    const float* __restrict__ b2, const float* __restrict__ b3,
    _Float16* __restrict__ wtg) {
  __shared__ __align__(16) char smem[24576];
  _Float16* ytF = (_Float16*)smem;        // [0, 6656): 32*104 fp16 (dead after MFMA loop)
  float* wal = (float*)smem;              // [0, 12288): 32*96 f32 (after ytF dead)
  float* wbl = wal + 3072;                // [12288, 24576)
  __shared__ float invv[96], biasv[96];

  const int t = threadIdx.x;
  const int wv = t >> 6, lane = t & 63, quad = lane >> 4, lr = lane & 15;
  const int wr = wv & 1, wc = wv >> 1;
  const long mblk = (long)blockIdx.x * 32;

  if (t < 96) {
    float iv = gamma[t] * rsqrtf(var[t] + 1e-5f);
    invv[t] = iv; biasv[t] = beta[t] - mean[t] * iv;
  }
  __syncthreads();

  // stage: sum 11 split-K slices + BN + ReLU -> ytF [32][104]; 768 quads / 256 threads
#pragma unroll
  for (int i = 0; i < 3; ++i) {
    int q = t + i * 256;                  // 0..767
    int m = q / 24, nq = (q - m * 24) * 4;
    long gbase = (mblk + m) * 96 + nq;
    float s0 = 0.f, s1 = 0.f, s2 = 0.f, s3 = 0.f;
#pragma unroll
    for (int ck = 0; ck < 11; ++ck) {
      half4 v = *(const half4*)(pacc + (long)ck * 1204224 + gbase);
      s0 += (float)v.x; s1 += (float)v.y; s2 += (float)v.z; s3 += (float)v.w;
    }
    half4 o;
    o.x = (_Float16)fmaxf(s0 * invv[nq + 0] + biasv[nq + 0], 0.f);
    o.y = (_Float16)fmaxf(s1 * invv[nq + 1] + biasv[nq + 1], 0.f);
    o.z = (_Float16)fmaxf(s2 * invv[nq + 2] + biasv[nq + 2], 0.f);
    o.w = (_Float16)fmaxf(s3 * invv[nq + 3] + biasv[nq + 3], 0.f);
    *(half4*)(ytF + m * 104 + nq) = o;
  }
  __syncthreads();

  floatx4 aa[3], ab[3];
#pragma unroll
  for (int j = 0; j < 3; ++j) { aa[j] = {0.f,0.f,0.f,0.f}; ab[j] = {0.f,0.f,0.f,0.f}; }
#pragma unroll
  for (int ks = 0; ks < 3; ++ks) {
    half8 af = *(const half8*)(ytF + (wr * 16 + lr) * 104 + ks * 32 + quad * 8);
#pragma unroll
    for (int j = 0; j < 3; ++j) {
      int n = (wc * 3 + j) * 16 + lr;
      int wo = n * 96 + ks * 32 + quad * 8;
      half8 b2v = *(const half8*)(w2f + wo);
      half8 b3v = *(const half8*)(w3f + wo);
      aa[j] = __builtin_amdgcn_mfma_f32_16x16x32_f16(af, b2v, aa[j], 0, 0, 0);
      ab[j] = __builtin_amdgcn_mfma_f32_16x16x32_f16(af, b3v, ab[j], 0, 0, 0);
    }
  }
  __syncthreads();   // ytF dead; smem becomes wal/wbl

#pragma unroll
  for (int j = 0; j < 3; ++j) {
    int n = (wc * 3 + j) * 16 + lr;
    float bb2 = b2[n], bb3 = b3[n];
#pragma unroll
    for (int r = 0; r < 4; ++r) {
      int m = wr * 16 + quad * 4 + r;
      wal[m * 96 + n] = aa[j][r] + bb2;
      wbl[m * 96 + n] = ab[j][r] + bb3;
    }
  }
  __syncthreads();

  // softmax: 32 rows x 64 (g,ns) units = 2048 / 256 threads
#pragma unroll
  for (int it = 0; it < 8; ++it) {
    int u = t + it * 256;
    int m = u >> 6, rest = u & 63;
    int g = rest >> 2, ns = rest & 3;
    int ns1 = ns >> 1, ns2 = ns & 1;
    float la[3], lb[3];
#pragma unroll
    for (int k = 0; k < 3; ++k) {
      la[k] = wal[m * 96 + (g * 3 + k) * 2 + ns1];
      lb[k] = wbl[m * 96 + (g * 3 + k) * 2 + ns2];
    }
    float lg[9], mx = -1e30f;
#pragma unroll
    for (int k1 = 0; k1 < 3; ++k1)
#pragma unroll
      for (int k2 = 0; k2 < 3; ++k2) {
        float v = la[k1] * lb[k2];
        lg[k1 * 3 + k2] = v;
        mx = v > mx ? v : mx;
      }
    float s = 0.f;
#pragma unroll
    for (int k = 0; k < 9; ++k) { lg[k] = __expf(lg[k] - mx); s += lg[k]; }
    float sc = 1.f / (9.f * s);
    _Float16* dst = wtg + (mblk + m) * 576 + g * 36 + ns * 9;
#pragma unroll
    for (int k = 0; k < 9; ++k) dst[k] = (_Float16)(lg[k] * sc);
  }
}

// ---------------- kApply: x + wt -> out ----------
// block = (b, h', wh(2), g(16)): 7168 blocks, 256 threads; 16 channels, 28 w-positions.
__global__ __launch_bounds__(256) void kApply(const float* __restrict__ x,
                                              const _Float16* __restrict__ wt,
                                              float* __restrict__ out) {
  int bid = blockIdx.x;
  int g = bid & 15;
  int wh = (bid >> 4) & 1;
  int h = (bid >> 5) % 56;
  int b = bid / 1792;
  int wbase = wh * 28, cbase = g * 16;

  __shared__ _Float16 xr[9 * 16 * 30];       // [(k2*3+k1)*480 + cl*30 + wc]
  __shared__ __align__(16) float wtb[28 * 36]; // [p*36 + (k1*3+k2)*4 + ns]
  __shared__ float ob[32 * 57];              // [(cl*2+ns1)*57 + p*2+ns2]

  int t = threadIdx.x;

  // fill xr: 144 rows x 30 cols; fully-batched loads
  {
    int wc = t & 31;
    int r0 = t >> 5;                    // 0..7
    int wr = wbase + wc - 1;
    bool wok = (wc < 30) & (wr >= 0) & (wr < 56);
    const long xb0 = ((long)b * 256 + cbase) * 3136;
    float vals[18];
#pragma unroll
    for (int i = 0; i < 18; ++i) {
      int row = r0 + i * 8;             // 0..143
      int kk = row >> 4, cl = row & 15;
      int k2 = kk / 3, k1 = kk - 3 * k2;
      int gr = (k2 * 56 + h) / 3 + k1 - 1;
      float v = 0.f;
      if (wok && gr >= 0 && gr < 56)
        v = x[xb0 + (long)cl * 3136 + gr * 56 + wr];
      vals[i] = v;
    }
#pragma unroll
    for (int i = 0; i < 18; ++i) {
      int row = r0 + i * 8;
      if (wc < 30) xr[row * 30 + wc] = (_Float16)vals[i];
    }
  }
  // wt -> wtb: wtb[p*36 + kk*4 + ns] = wt[(m0+p)*576 + g*36 + ns*9 + kk]
  {
    long m0 = ((long)(b * 56 + h)) * 56 + wbase;
    float vals[4];
#pragma unroll
    for (int i = 0; i < 4; ++i) {
      int idx = t + i * 256;
      if (idx < 1008) {
        int p = idx / 36, r36 = idx - p * 36;
        int kk = r36 >> 2, ns = r36 & 3;
        vals[i] = (float)wt[(m0 + p) * 576 + g * 36 + ns * 9 + kk];
      }
    }
#pragma unroll
    for (int i = 0; i < 4; ++i) {
      int idx = t + i * 256;
      if (idx < 1008) wtb[idx] = vals[i];
    }
  }
  __syncthreads();

  // compute: thread owns (cl, p); 4 ns accumulators; float4 weight reads
  {
    int j2r[3];
#pragma unroll
    for (int k2 = 0; k2 < 3; ++k2) j2r[k2] = (k2 * 56 + h) % 3;
#pragma unroll
    for (int i = 0; i < 2; ++i) {
      int idx = i * 256 + t;
      int cl = idx & 15;
      int p = idx >> 4;                 // 0..31
      if (p < 28) {
        float a0 = 0.f, a1 = 0.f, a2 = 0.f, a3 = 0.f;
#pragma unroll
        for (int k1 = 0; k1 < 3; ++k1)
#pragma unroll
          for (int k2 = 0; k2 < 3; ++k2) {
            float xv = (float)xr[(k2 * 3 + k1) * 480 + cl * 30 + p + j2r[k2]];
            float4 wv = *(const float4*)&wtb[p * 36 + (k1 * 3 + k2) * 4];
            a0 += xv * wv.x; a1 += xv * wv.y; a2 += xv * wv.z; a3 += xv * wv.w;
          }
        int ob0 = cl * 114 + p * 2;
        ob[ob0] = a0;
        ob[ob0 + 1] = a1;
        ob[ob0 + 57] = a2;
        ob[ob0 + 58] = a3;
      }
    }
  }
  __syncthreads();

  // writeout: 32 rows x 56 cols, coalesced
  {
    int wo = t & 63;
    int r0 = t >> 6;                    // 0..3
    const long obase = (((long)b * 256 + cbase) * 112 + 2 * h) * 112 + wh * 56;
#pragma unroll
    for (int i = 0; i < 8; ++i) {
      int row = r0 + i * 4;             // 0..31
      if (wo < 56) {
        int cli = row >> 1, n1 = row & 1;
        out[obase + cli * 12544 + n1 * 112 + wo] = ob[row * 57 + wo];
      }
    }
  }
}

extern "C" void kernel_launch(void* const* d_in, const int* in_sizes, int n_in,
                              void* d_out, int out_size, void* d_ws, size_t ws_size,
                              hipStream_t stream) {
  const float* x = (const float*)d_in[0];
  const float* w1 = (const float*)d_in[1];
  const float* gamma = (const float*)d_in[2];
  const float* beta = (const float*)d_in[3];
  const float* mean = (const float*)d_in[4];
  const float* var = (const float*)d_in[5];
  const float* w2 = (const float*)d_in[6];
  const float* b2 = (const float*)d_in[7];
  const float* w3 = (const float*)d_in[8];
  const float* b3 = (const float*)d_in[9];
  float* out = (float*)d_out;

  // workspace layout (bytes), total ~96.8 MB:
  //   w1f fp16:   [0, 405504)
  //   w2f fp16:   [405504, 423936)
  //   w3f fp16:   [423936, 442368)
  //   wtg fp16:   [442368, 14893056)
  //   descF fp16: [14893056, 67878912)
  //   pacc fp16:  [67878912, 94371840)   (11 split-K slices)
  _Float16* w1f = (_Float16*)d_ws;
  _Float16* w2f = w1f + 202752;
  _Float16* w3f = w2f + 9216;
  _Float16* wtg = (_Float16*)((char*)d_ws + 442368);
  _Float16* descF = (_Float16*)((char*)d_ws + 14893056);
  _Float16* pacc = (_Float16*)((char*)d_ws + 67878912);

  hipLaunchKernelGGL(kW, dim3(864), dim3(256), 0, stream, w1, w2, w3, w1f, w2f, w3f);
  hipLaunchKernelGGL(kDesc, dim3(3584), dim3(512), 0, stream, x, descF);
  hipLaunchKernelGGL(kGemm1, dim3(2156), dim3(256), 0, stream, descF, w1f, pacc);
  hipLaunchKernelGGL(kGemm2, dim3(392), dim3(256), 0, stream,
                     pacc, gamma, beta, mean, var, w2f, w3f, b2, b3, wtg);
  hipLaunchKernelGGL(kApply, dim3(7168), dim3(256), 0, stream, x, wtg, out);
}

// Round 5
// 185.117 us; speedup vs baseline: 1.2697x; 1.0142x over previous
//
#include <hip/hip_runtime.h>

typedef __attribute__((ext_vector_type(8))) _Float16 half8;
typedef __attribute__((ext_vector_type(4))) _Float16 half4;
typedef __attribute__((ext_vector_type(4))) float floatx4;

// async global->LDS DMA, 16B per lane; lds must be wave-uniform base (+lane*16 implicit)
__device__ inline void gld16(const _Float16* g, _Float16* lds) {
  __builtin_amdgcn_global_load_lds(
      (const __attribute__((address_space(1))) unsigned int*)g,
      (__attribute__((address_space(3))) unsigned int*)lds, 16, 0, 0);
}

// ---- per-unit gather for the unfold tile: idx in [0,2016) -> (half4 value, LDS offset) --
// tap(k1,k2) at (h',w') = x[row=(k2*56+h')/3+k1-1, col=w'+(k2*56+h')%3-1], zero-pad.
// xb row stride = 72 halves (144 B); chunk c (8 halves) stored at c ^ (kk&7).
__device__ __forceinline__ void descCalc(const float* __restrict__ x, long xp, int h,
                                         int idx, half4& hv, int& off) {
  int r = idx / 14, c4 = idx - r * 14;
  int kk = r >> 4, ch = r & 15;
  int k2 = kk / 3, k1 = kk - 3 * k2;
  int t2 = k2 * 56 + h;
  int q3 = t2 / 3;
  int gr = q3 + k1 - 1;
  int s = t2 - q3 * 3;                  // column shift for this row's k2
  int col0 = c4 * 4;
  hv[0] = hv[1] = hv[2] = hv[3] = (_Float16)0.f;
  if (gr >= 0 && gr < 56) {
    long rb = xp + (long)ch * 3136 + (long)gr * 56 + (s - 1) + col0;
    bool interior = (col0 > 0 || s > 0) && (c4 < 13 || s < 2);
    if (interior) {
      float fv[4];
      __builtin_memcpy(fv, x + rb, 16);
      hv[0] = (_Float16)fv[0]; hv[1] = (_Float16)fv[1];
      hv[2] = (_Float16)fv[2]; hv[3] = (_Float16)fv[3];
    } else {
#pragma unroll
      for (int e = 0; e < 4; ++e) {
        int cg = col0 + e + s - 1;      // global x column
        float v = 0.f;
        if ((unsigned)cg < 56u) v = x[rb + e];
        hv[e] = (_Float16)v;
      }
    }
  }
  off = r * 144 + (((c4 >> 1) ^ (kk & 7)) << 4) + (c4 & 1) * 8;
}

// ---------------- kDescW: pipelined 4-g descriptor builder + weight-cast side blocks ----
// blocks [0,896): (gq 4) x (h 56) x (b 4); 512 threads; 4 g's per block, double-buffered.
// blocks [896,1328): fp32->fp16 weight casts (the old kW), 512 threads each.
__global__ __launch_bounds__(512) void kDescW(const float* __restrict__ x,
                                              const float* __restrict__ w1,
                                              const float* __restrict__ w2,
                                              const float* __restrict__ w3,
                                              _Float16* __restrict__ descF,
                                              _Float16* __restrict__ w1f,
                                              _Float16* __restrict__ w2f,
                                              _Float16* __restrict__ w3f) {
  __shared__ __align__(16) _Float16 xb[2][144 * 72];  // 2 x 20736 B
  __shared__ __align__(16) int tOf[132][4];           // enc = row*144 | key (key=kk&7)

  const int t = threadIdx.x;
  const int bid = blockIdx.x;

  if (bid >= 896) {                     // ---- weight-cast blocks ----
    int i = (bid - 896) * 512 + t;
    if (i < 202752) w1f[i] = (_Float16)w1[i];
    else if (i < 211968) w2f[i - 202752] = (_Float16)w2[i - 202752];
    else if (i < 221184) w3f[i - 211968] = (_Float16)w3[i - 211968];
    return;
  }

  const int gq = bid & 3;
  const int rest = bid >> 2;
  const int h = rest % 56;
  const int b = rest / 56;

  // ---- tap-offset table (g-independent) ----
  if (t < 132) {
    int dl = t;
    int r0, r1, r2, r3;
    if (dl < 36) {                       // x1: max over 4 sub-channels
      int a3 = dl / 9, rem = dl % 9, k1 = rem / 3, k2 = rem % 3;
      int br = (k2 * 3 + k1) * 16 + a3;
      r0 = br; r1 = br + 4; r2 = br + 8; r3 = br + 12;
    } else if (dl < 84) {                // x2: max over k1
      int u = dl - 36, gc = u / 3, k2 = u % 3;
      r0 = (k2 * 3 + 0) * 16 + gc;
      r1 = (k2 * 3 + 1) * 16 + gc;
      r2 = (k2 * 3 + 2) * 16 + gc;
      r3 = r0;
    } else {                             // x3: max over k2
      int u = dl - 84, gc = u / 3, k1 = u % 3;
      r0 = (0 + k1) * 16 + gc;
      r1 = (3 + k1) * 16 + gc;
      r2 = (6 + k1) * 16 + gc;
      r3 = r0;
    }
    tOf[dl][0] = r0 * 144 + ((r0 >> 4) & 7);
    tOf[dl][1] = r1 * 144 + ((r1 >> 4) & 7);
    tOf[dl][2] = r2 * 144 + ((r2 >> 4) & 7);
    tOf[dl][3] = r3 * 144 + ((r3 >> 4) & 7);
  }

  // ---- prologue: fill buf0 for g0 ----
  {
    const int g0 = gq * 4;
    const long xp = ((long)b * 256 + g0 * 16) * 3136;
#pragma unroll
    for (int i = 0; i < 4; ++i) {
      int idx = t + i * 512;
      if (idx < 2016) {
        half4 hv; int off;
        descCalc(x, xp, h, idx, hv, off);
        *(half4*)((char*)xb[0] + off) = hv;
      }
    }
  }
  __syncthreads();

  const long m00 = ((long)(b * 56 + h)) * 56;
  int cur = 0;
#pragma unroll
  for (int gi = 0; gi < 4; ++gi) {
    const int g = gq * 4 + gi;

    // ---- prefetch next g's gathers into registers (latency hides under compute) ----
    half4 pv0, pv1, pv2, pv3;
    int po0 = -1, po1 = -1, po2 = -1, po3 = -1;
    if (gi < 3) {
      const long xp = ((long)b * 256 + (g + 1) * 16) * 3136;
      {
        int idx = t;            descCalc(x, xp, h, idx, pv0, po0);
      }
      { int idx = t + 512;      descCalc(x, xp, h, idx, pv1, po1); }
      { int idx = t + 1024;     descCalc(x, xp, h, idx, pv2, po2); }
      { int idx = t + 1536;     if (idx < 2016) descCalc(x, xp, h, idx, pv3, po3); else po3 = -1; }
    }

    // ---- compute current g: unit = (pc, dl); 924 units / 512 threads ----
#pragma unroll
    for (int i = 0; i < 2; ++i) {
      int idx = t + i * 512;
      if (idx < 924) {
        int pc = idx / 132, dl = idx - pc * 132;
        const int4 of = *(const int4*)tOf[dl];
        const char* xbb = (const char*)xb[cur];
        half8 v0 = *(const half8*)(xbb + (of.x & ~15) + ((pc ^ (of.x & 15)) << 4));
        half8 v1 = *(const half8*)(xbb + (of.y & ~15) + ((pc ^ (of.y & 15)) << 4));
        half8 v2 = *(const half8*)(xbb + (of.z & ~15) + ((pc ^ (of.z & 15)) << 4));
        half8 v3 = *(const half8*)(xbb + (of.w & ~15) + ((pc ^ (of.w & 15)) << 4));
        half8 a = __builtin_elementwise_max(v0, v1);
        half8 c = __builtin_elementwise_max(v2, v3);
        half8 r8 = __builtin_elementwise_max(a, c);
        int dg = (dl < 36) ? (g * 36 + dl)
               : (dl < 84) ? (576 + g * 48 + (dl - 36))
                           : (1344 + g * 48 + (dl - 84));
        _Float16* dp = descF + (m00 + pc * 8) * 2112 + dg;
#pragma unroll
        for (int e = 0; e < 8; ++e) dp[(long)e * 2112] = r8[e];
      }
    }

    // ---- commit prefetch to the other buffer ----
    if (gi < 3) {
      char* dst = (char*)xb[cur ^ 1];
      *(half4*)(dst + po0) = pv0;
      *(half4*)(dst + po1) = pv1;
      *(half4*)(dst + po2) = pv2;
      if (po3 >= 0) *(half4*)(dst + po3) = pv3;
    }
    __syncthreads();
    cur ^= 1;
  }
}

// ---------------- kGemm1: split-K partial GEMM, LDS-staged via global_load_lds ----------
// grid = 196 Mtiles x 11 K-chunks = 2156 blocks; 256 threads; M=64, N=96, K-chunk=192, BK=32.
__global__ __launch_bounds__(256) void kGemm1(
    const _Float16* __restrict__ descF, const _Float16* __restrict__ w1f,
    _Float16* __restrict__ pacc) {
  __shared__ _Float16 Ab[2][64 * 32];   // [row*32 + c*8]
  __shared__ _Float16 Bb[2][96 * 32];   // [n*32 + c*8]
  const int t = threadIdx.x;
  const int wv = t >> 6, lane = t & 63, quad = lane >> 4, lr = lane & 15;
  const int mt = blockIdx.x / 11, ck = blockIdx.x % 11;
  const long mblk = (long)mt * 64;

  const long agbase = (mblk + (t >> 2)) * 2112 + ck * 192 + (t & 3) * 8;
  const long bg0 = (long)(t >> 2) * 2112 + ck * 192 + (t & 3) * 8;
  const long bg1 = (long)((256 + t) >> 2) * 2112 + ck * 192 + (t & 3) * 8;
  const int wslot = (t >> 6) * 512;     // wave-uniform LDS base (halves)

  floatx4 acc[6];
#pragma unroll
  for (int j = 0; j < 6; ++j) acc[j] = {0.f, 0.f, 0.f, 0.f};

  gld16(descF + agbase, &Ab[0][wslot]);
  gld16(w1f + bg0, &Bb[0][wslot]);
  if (t < 128) gld16(w1f + bg1, &Bb[0][2048 + wslot]);

  int buf = 0;
  for (int kt = 0; kt < 6; ++kt) {
    __syncthreads();
    if (kt < 5) {
      int off = (kt + 1) * 32;
      gld16(descF + agbase + off, &Ab[buf ^ 1][wslot]);
      gld16(w1f + bg0 + off, &Bb[buf ^ 1][wslot]);
      if (t < 128) gld16(w1f + bg1 + off, &Bb[buf ^ 1][2048 + wslot]);
    }
    half8 af = *(const half8*)(&Ab[buf][(wv * 16 + lr) * 32 + quad * 8]);
#pragma unroll
    for (int j = 0; j < 6; ++j) {
      half8 bf = *(const half8*)(&Bb[buf][(j * 16 + lr) * 32 + quad * 8]);
      acc[j] = __builtin_amdgcn_mfma_f32_16x16x32_f16(af, bf, acc[j], 0, 0, 0);
    }
    buf ^= 1;
  }

  _Float16* pp = pacc + (long)(ck * 196 + mt) * 6144;
#pragma unroll
  for (int j = 0; j < 6; ++j)
#pragma unroll
    for (int r = 0; r < 4; ++r)
      pp[(wv * 16 + quad * 4 + r) * 96 + j * 16 + lr] = (_Float16)acc[j][r];
}

// ---------------- kGemm2 v2: reduce(11 pacc)+BN+ReLU -> y tile -> GEMM2 -> softmax ------
// grid = 392 blocks x 256 threads; 32 rows per block; waves = 2(row-half) x 2(col-half).
__global__ __launch_bounds__(256) void kGemm2(
    const _Float16* __restrict__ pacc,
    const float* __restrict__ gamma, const float* __restrict__ beta,
    const float* __restrict__ mean, const float* __restrict__ var,
    const _Float16* __restrict__ w2f, const _Float16* __restrict__ w3f,
    const float* __restrict__ b2, const float* __restrict__ b3,
    _Float16* __restrict__ wtg) {
  __shared__ __align__(16) char smem[24576];
  _Float16* ytF = (_Float16*)smem;        // [0, 6656): 32*104 fp16 (dead after MFMA loop)
  float* wal = (float*)smem;              // [0, 12288): 32*96 f32 (after ytF dead)
  float* wbl = wal + 3072;                // [12288, 24576)
  __shared__ float invv[96], biasv[96];

  const int t = threadIdx.x;
  const int wv = t >> 6, lane = t & 63, quad = lane >> 4, lr = lane & 15;
  const int wr = wv & 1, wc = wv >> 1;
  const long mblk = (long)blockIdx.x * 32;

  if (t < 96) {
    float iv = gamma[t] * rsqrtf(var[t] + 1e-5f);
    invv[t] = iv; biasv[t] = beta[t] - mean[t] * iv;
  }
  __syncthreads();

  // stage: sum 11 split-K slices + BN + ReLU -> ytF [32][104]; 768 quads / 256 threads
#pragma unroll
  for (int i = 0; i < 3; ++i) {
    int q = t + i * 256;                  // 0..767
    int m = q / 24, nq = (q - m * 24) * 4;
    long gbase = (mblk + m) * 96 + nq;
    float s0 = 0.f, s1 = 0.f, s2 = 0.f, s3 = 0.f;
#pragma unroll
    for (int ck = 0; ck < 11; ++ck) {
      half4 v = *(const half4*)(pacc + (long)ck * 1204224 + gbase);
      s0 += (float)v.x; s1 += (float)v.y; s2 += (float)v.z; s3 += (float)v.w;
    }
    half4 o;
    o.x = (_Float16)fmaxf(s0 * invv[nq + 0] + biasv[nq + 0], 0.f);
    o.y = (_Float16)fmaxf(s1 * invv[nq + 1] + biasv[nq + 1], 0.f);
    o.z = (_Float16)fmaxf(s2 * invv[nq + 2] + biasv[nq + 2], 0.f);
    o.w = (_Float16)fmaxf(s3 * invv[nq + 3] + biasv[nq + 3], 0.f);
    *(half4*)(ytF + m * 104 + nq) = o;
  }
  __syncthreads();

  floatx4 aa[3], ab[3];
#pragma unroll
  for (int j = 0; j < 3; ++j) { aa[j] = {0.f,0.f,0.f,0.f}; ab[j] = {0.f,0.f,0.f,0.f}; }
#pragma unroll
  for (int ks = 0; ks < 3; ++ks) {
    half8 af = *(const half8*)(ytF + (wr * 16 + lr) * 104 + ks * 32 + quad * 8);
#pragma unroll
    for (int j = 0; j < 3; ++j) {
      int n = (wc * 3 + j) * 16 + lr;
      int wo = n * 96 + ks * 32 + quad * 8;
      half8 b2v = *(const half8*)(w2f + wo);
      half8 b3v = *(const half8*)(w3f + wo);
      aa[j] = __builtin_amdgcn_mfma_f32_16x16x32_f16(af, b2v, aa[j], 0, 0, 0);
      ab[j] = __builtin_amdgcn_mfma_f32_16x16x32_f16(af, b3v, ab[j], 0, 0, 0);
    }
  }
  __syncthreads();   // ytF dead; smem becomes wal/wbl

#pragma unroll
  for (int j = 0; j < 3; ++j) {
    int n = (wc * 3 + j) * 16 + lr;
    float bb2 = b2[n], bb3 = b3[n];
#pragma unroll
    for (int r = 0; r < 4; ++r) {
      int m = wr * 16 + quad * 4 + r;
      wal[m * 96 + n] = aa[j][r] + bb2;
      wbl[m * 96 + n] = ab[j][r] + bb3;
    }
  }
  __syncthreads();

  // softmax: 32 rows x 64 (g,ns) units = 2048 / 256 threads
#pragma unroll
  for (int it = 0; it < 8; ++it) {
    int u = t + it * 256;
    int m = u >> 6, rest = u & 63;
    int g = rest >> 2, ns = rest & 3;
    int ns1 = ns >> 1, ns2 = ns & 1;
    float la[3], lb[3];
#pragma unroll
    for (int k = 0; k < 3; ++k) {
      la[k] = wal[m * 96 + (g * 3 + k) * 2 + ns1];
      lb[k] = wbl[m * 96 + (g * 3 + k) * 2 + ns2];
    }
    float lg[9], mx = -1e30f;
#pragma unroll
    for (int k1 = 0; k1 < 3; ++k1)
#pragma unroll
      for (int k2 = 0; k2 < 3; ++k2) {
        float v = la[k1] * lb[k2];
        lg[k1 * 3 + k2] = v;
        mx = v > mx ? v : mx;
      }
    float s = 0.f;
#pragma unroll
    for (int k = 0; k < 9; ++k) { lg[k] = __expf(lg[k] - mx); s += lg[k]; }
    float sc = 1.f / (9.f * s);
    _Float16* dst = wtg + (mblk + m) * 576 + g * 36 + ns * 9;
#pragma unroll
    for (int k = 0; k < 9; ++k) dst[k] = (_Float16)(lg[k] * sc);
  }
}

// ---------------- kApply: x + wt -> out ----------
// block = (b, h', wh(2), g(16)): 7168 blocks, 256 threads; 16 channels, 28 w-positions.
__global__ __launch_bounds__(256) void kApply(const float* __restrict__ x,
                                              const _Float16* __restrict__ wt,
                                              float* __restrict__ out) {
  int bid = blockIdx.x;
  int g = bid & 15;
  int wh = (bid >> 4) & 1;
  int h = (bid >> 5) % 56;
  int b = bid / 1792;
  int wbase = wh * 28, cbase = g * 16;

  __shared__ _Float16 xr[9 * 16 * 30];       // [(k2*3+k1)*480 + cl*30 + wc]
  __shared__ __align__(16) float wtb[28 * 36]; // [p*36 + (k1*3+k2)*4 + ns]
  __shared__ float ob[32 * 57];              // [(cl*2+ns1)*57 + p*2+ns2]

  int t = threadIdx.x;

  // fill xr: 144 rows x 30 cols; fully-batched loads
  {
    int wc = t & 31;
    int r0 = t >> 5;                    // 0..7
    int wr = wbase + wc - 1;
    bool wok = (wc < 30) & (wr >= 0) & (wr < 56);
    const long xb0 = ((long)b * 256 + cbase) * 3136;
    float vals[18];
#pragma unroll
    for (int i = 0; i < 18; ++i) {
      int row = r0 + i * 8;             // 0..143
      int kk = row >> 4, cl = row & 15;
      int k2 = kk / 3, k1 = kk - 3 * k2;
      int gr = (k2 * 56 + h) / 3 + k1 - 1;
      float v = 0.f;
      if (wok && gr >= 0 && gr < 56)
        v = x[xb0 + (long)cl * 3136 + gr * 56 + wr];
      vals[i] = v;
    }
#pragma unroll
    for (int i = 0; i < 18; ++i) {
      int row = r0 + i * 8;
      if (wc < 30) xr[row * 30 + wc] = (_Float16)vals[i];
    }
  }
  // wt -> wtb: wtb[p*36 + kk*4 + ns] = wt[(m0+p)*576 + g*36 + ns*9 + kk]
  {
    long m0 = ((long)(b * 56 + h)) * 56 + wbase;
    float vals[4];
#pragma unroll
    for (int i = 0; i < 4; ++i) {
      int idx = t + i * 256;
      if (idx < 1008) {
        int p = idx / 36, r36 = idx - p * 36;
        int kk = r36 >> 2, ns = r36 & 3;
        vals[i] = (float)wt[(m0 + p) * 576 + g * 36 + ns * 9 + kk];
      }
    }
#pragma unroll
    for (int i = 0; i < 4; ++i) {
      int idx = t + i * 256;
      if (idx < 1008) wtb[idx] = vals[i];
    }
  }
  __syncthreads();

  // compute: thread owns (cl, p); 4 ns accumulators; float4 weight reads
  {
    int j2r[3];
#pragma unroll
    for (int k2 = 0; k2 < 3; ++k2) j2r[k2] = (k2 * 56 + h) % 3;
#pragma unroll
    for (int i = 0; i < 2; ++i) {
      int idx = i * 256 + t;
      int cl = idx & 15;
      int p = idx >> 4;                 // 0..31
      if (p < 28) {
        float a0 = 0.f, a1 = 0.f, a2 = 0.f, a3 = 0.f;
#pragma unroll
        for (int k1 = 0; k1 < 3; ++k1)
#pragma unroll
          for (int k2 = 0; k2 < 3; ++k2) {
            float xv = (float)xr[(k2 * 3 + k1) * 480 + cl * 30 + p + j2r[k2]];
            float4 wv = *(const float4*)&wtb[p * 36 + (k1 * 3 + k2) * 4];
            a0 += xv * wv.x; a1 += xv * wv.y; a2 += xv * wv.z; a3 += xv * wv.w;
          }
        int ob0 = cl * 114 + p * 2;
        ob[ob0] = a0;
        ob[ob0 + 1] = a1;
        ob[ob0 + 57] = a2;
        ob[ob0 + 58] = a3;
      }
    }
  }
  __syncthreads();

  // writeout: 32 rows x 56 cols, coalesced
  {
    int wo = t & 63;
    int r0 = t >> 6;                    // 0..3
    const long obase = (((long)b * 256 + cbase) * 112 + 2 * h) * 112 + wh * 56;
#pragma unroll
    for (int i = 0; i < 8; ++i) {
      int row = r0 + i * 4;             // 0..31
      if (wo < 56) {
        int cli = row >> 1, n1 = row & 1;
        out[obase + cli * 12544 + n1 * 112 + wo] = ob[row * 57 + wo];
      }
    }
  }
}

extern "C" void kernel_launch(void* const* d_in, const int* in_sizes, int n_in,
                              void* d_out, int out_size, void* d_ws, size_t ws_size,
                              hipStream_t stream) {
  const float* x = (const float*)d_in[0];
  const float* w1 = (const float*)d_in[1];
  const float* gamma = (const float*)d_in[2];
  const float* beta = (const float*)d_in[3];
  const float* mean = (const float*)d_in[4];
  const float* var = (const float*)d_in[5];
  const float* w2 = (const float*)d_in[6];
  const float* b2 = (const float*)d_in[7];
  const float* w3 = (const float*)d_in[8];
  const float* b3 = (const float*)d_in[9];
  float* out = (float*)d_out;

  // workspace layout (bytes), total ~96.8 MB:
  //   w1f fp16:   [0, 405504)
  //   w2f fp16:   [405504, 423936)
  //   w3f fp16:   [423936, 442368)
  //   wtg fp16:   [442368, 14893056)
  //   descF fp16: [14893056, 67878912)
  //   pacc fp16:  [67878912, 94371840)   (11 split-K slices)
  _Float16* w1f = (_Float16*)d_ws;
  _Float16* w2f = w1f + 202752;
  _Float16* w3f = w2f + 9216;
  _Float16* wtg = (_Float16*)((char*)d_ws + 442368);
  _Float16* descF = (_Float16*)((char*)d_ws + 14893056);
  _Float16* pacc = (_Float16*)((char*)d_ws + 67878912);

  hipLaunchKernelGGL(kDescW, dim3(1328), dim3(512), 0, stream,
                     x, w1, w2, w3, descF, w1f, w2f, w3f);
  hipLaunchKernelGGL(kGemm1, dim3(2156), dim3(256), 0, stream, descF, w1f, pacc);
  hipLaunchKernelGGL(kGemm2, dim3(392), dim3(256), 0, stream,
                     pacc, gamma, beta, mean, var, w2f, w3f, b2, b3, wtg);
  hipLaunchKernelGGL(kApply, dim3(7168), dim3(256), 0, stream, x, wtg, out);
}

// Round 6
// 182.648 us; speedup vs baseline: 1.2869x; 1.0135x over previous
//
#include <hip/hip_runtime.h>

typedef __attribute__((ext_vector_type(8))) _Float16 half8;
typedef __attribute__((ext_vector_type(4))) _Float16 half4;
typedef __attribute__((ext_vector_type(2))) _Float16 half2v;
typedef __attribute__((ext_vector_type(4))) float floatx4;

// async global->LDS DMA, 16B per lane; lds must be wave-uniform base (+lane*16 implicit)
__device__ inline void gld16(const _Float16* g, _Float16* lds) {
  __builtin_amdgcn_global_load_lds(
      (const __attribute__((address_space(1))) unsigned int*)g,
      (__attribute__((address_space(3))) unsigned int*)lds, 16, 0, 0);
}

// ---------------- kDescC: descriptor builder with 4dl x 8w tiled stores ----------------
// blocks [0,3584): (g 16) x (h 56) x (b 4), 256 threads.
// blocks [3584,4448): fp32->fp16 weight casts (old kW).
// tap(k1,k2) at (h',w') = x[row=(k2*56+h')/3+k1-1, col=w'+(k2*56+h')%3-1], zero-pad.
// Compute: thread = (pc 0..6, dlc 0..32): 4 consecutive dl x 8 w; 16 ds_read_b128 ->
// pk-max -> 4x8 register transpose -> 8x 8B stores (dg contiguous over the 4 dl).
__global__ __launch_bounds__(256) void kDescC(const float* __restrict__ x,
                                              const float* __restrict__ w1,
                                              const float* __restrict__ w2,
                                              const float* __restrict__ w3,
                                              _Float16* __restrict__ descF,
                                              _Float16* __restrict__ w1f,
                                              _Float16* __restrict__ w2f,
                                              _Float16* __restrict__ w3f) {
  const int bid = blockIdx.x;
  const int t = threadIdx.x;

  if (bid >= 3584) {                    // ---- weight-cast blocks ----
    int i = (bid - 3584) * 256 + t;
    if (i < 202752) w1f[i] = (_Float16)w1[i];
    else if (i < 211968) w2f[i - 202752] = (_Float16)w2[i - 202752];
    else if (i < 221184) w3f[i - 211968] = (_Float16)w3[i - 211968];
    return;
  }

  int g = bid & 15;
  int h = (bid >> 4) % 56;
  int b = bid / 896;

  // xb row stride = 72 halves (144 B). chunk c (8 halves) stored at c ^ (kk&7).
  __shared__ __align__(16) _Float16 xb[144 * 72];   // 20736 B
  __shared__ __align__(16) int tOf[132][4];         // enc = row*144 | key (key=(row>>4)&7)

  // ---- tap-offset table (132 threads) ----
  if (t < 132) {
    int dl = t;
    int r0, r1, r2, r3;
    if (dl < 36) {                       // x1: max over 4 sub-channels
      int a3 = dl / 9, rem = dl % 9, k1 = rem / 3, k2 = rem % 3;
      int br = (k2 * 3 + k1) * 16 + a3;
      r0 = br; r1 = br + 4; r2 = br + 8; r3 = br + 12;
    } else if (dl < 84) {                // x2: max over k1
      int u = dl - 36, gc = u / 3, k2 = u % 3;
      r0 = (k2 * 3 + 0) * 16 + gc;
      r1 = (k2 * 3 + 1) * 16 + gc;
      r2 = (k2 * 3 + 2) * 16 + gc;
      r3 = r0;
    } else {                             // x3: max over k2
      int u = dl - 84, gc = u / 3, k1 = u % 3;
      r0 = (0 + k1) * 16 + gc;
      r1 = (3 + k1) * 16 + gc;
      r2 = (6 + k1) * 16 + gc;
      r3 = r0;
    }
    tOf[dl][0] = r0 * 144 + ((r0 >> 4) & 7);
    tOf[dl][1] = r1 * 144 + ((r1 >> 4) & 7);
    tOf[dl][2] = r2 * 144 + ((r2 >> 4) & 7);
    tOf[dl][3] = r3 * 144 + ((r3 >> 4) & 7);
  }

  // ---- fill xb: 144 rows x 56 cols (per-k2 shift folded), float4 loads ----
  {
    const long xp = ((long)b * 256 + g * 16) * 3136;
#pragma unroll
    for (int i = 0; i < 8; ++i) {
      int idx = t + i * 256;
      if (idx < 2016) {
        int r = idx / 14, c4 = idx - r * 14;
        int kk = r >> 4, ch = r & 15;
        int k2 = kk / 3, k1 = kk - 3 * k2;
        int t2 = k2 * 56 + h;
        int q3 = t2 / 3;
        int gr = q3 + k1 - 1;
        int s = t2 - q3 * 3;              // column shift for this row's k2
        int col0 = c4 * 4;
        half4 hv;
        if (gr >= 0 && gr < 56) {
          long rb = xp + (long)ch * 3136 + (long)gr * 56 + (s - 1) + col0;
          bool interior = (col0 > 0 || s > 0) && (c4 < 13 || s < 2);
          if (interior) {
            float fv[4];
            __builtin_memcpy(fv, x + rb, 16);
            hv[0] = (_Float16)fv[0]; hv[1] = (_Float16)fv[1];
            hv[2] = (_Float16)fv[2]; hv[3] = (_Float16)fv[3];
          } else {
#pragma unroll
            for (int e = 0; e < 4; ++e) {
              int cg = col0 + e + s - 1;   // global x column
              float v = 0.f;
              if ((unsigned)cg < 56u) v = x[rb + e];
              hv[e] = (_Float16)v;
            }
          }
        } else {
#pragma unroll
          for (int e = 0; e < 4; ++e) hv[e] = (_Float16)0.f;
        }
        int key = kk & 7;
        int chunk = (c4 >> 1) ^ key;
        *(half4*)((char*)xb + r * 144 + chunk * 16 + (c4 & 1) * 8) = hv;
      }
    }
  }
  __syncthreads();

  // ---- compute + transpose + store: 231 units = (pc 0..6) x (dlc 0..32) ----
  // unit: 4 consecutive dl (dlc*4..+3) x 8 w (pc*8..+7); dg contiguous over the 4 dl
  // (segment bounds 36 and 84 are multiples of 4, so no chunk crosses a segment).
  const long m00 = ((long)(b * 56 + h)) * 56;
  if (t < 231) {
    int pc = t / 33, dlc = t - pc * 33;
    int dl0 = dlc * 4;
    half8 r8s[4];
    const char* xbb = (const char*)xb;
#pragma unroll
    for (int i = 0; i < 4; ++i) {
      const int4 of = *(const int4*)tOf[dl0 + i];
      half8 v0 = *(const half8*)(xbb + (of.x & ~15) + ((pc ^ (of.x & 15)) << 4));
      half8 v1 = *(const half8*)(xbb + (of.y & ~15) + ((pc ^ (of.y & 15)) << 4));
      half8 v2 = *(const half8*)(xbb + (of.z & ~15) + ((pc ^ (of.z & 15)) << 4));
      half8 v3 = *(const half8*)(xbb + (of.w & ~15) + ((pc ^ (of.w & 15)) << 4));
      half8 a = __builtin_elementwise_max(v0, v1);
      half8 c = __builtin_elementwise_max(v2, v3);
      r8s[i] = __builtin_elementwise_max(a, c);
    }
    int dg0 = (dlc < 9)  ? (g * 36 + dl0)
            : (dlc < 21) ? (576 + g * 48 + (dl0 - 36))
                         : (1344 + g * 48 + (dl0 - 84));
    _Float16* dp = descF + (m00 + pc * 8) * 2112 + dg0;
#pragma unroll
    for (int e = 0; e < 8; ++e) {
      half4 o;
      o[0] = r8s[0][e]; o[1] = r8s[1][e]; o[2] = r8s[2][e]; o[3] = r8s[3][e];
      *(half4*)(dp + (long)e * 2112) = o;   // 8B store, 8B-aligned
    }
  }
}

// ---------------- kGemm1: split-K partial GEMM, LDS-staged via global_load_lds ----------
// grid = 196 Mtiles x 11 K-chunks = 2156 blocks; 256 threads; M=64, N=96, K-chunk=192, BK=32.
__global__ __launch_bounds__(256) void kGemm1(
    const _Float16* __restrict__ descF, const _Float16* __restrict__ w1f,
    _Float16* __restrict__ pacc) {
  __shared__ _Float16 Ab[2][64 * 32];   // [row*32 + c*8]
  __shared__ _Float16 Bb[2][96 * 32];   // [n*32 + c*8]
  const int t = threadIdx.x;
  const int wv = t >> 6, lane = t & 63, quad = lane >> 4, lr = lane & 15;
  const int mt = blockIdx.x / 11, ck = blockIdx.x % 11;
  const long mblk = (long)mt * 64;

  const long agbase = (mblk + (t >> 2)) * 2112 + ck * 192 + (t & 3) * 8;
  const long bg0 = (long)(t >> 2) * 2112 + ck * 192 + (t & 3) * 8;
  const long bg1 = (long)((256 + t) >> 2) * 2112 + ck * 192 + (t & 3) * 8;
  const int wslot = (t >> 6) * 512;     // wave-uniform LDS base (halves)

  floatx4 acc[6];
#pragma unroll
  for (int j = 0; j < 6; ++j) acc[j] = {0.f, 0.f, 0.f, 0.f};

  gld16(descF + agbase, &Ab[0][wslot]);
  gld16(w1f + bg0, &Bb[0][wslot]);
  if (t < 128) gld16(w1f + bg1, &Bb[0][2048 + wslot]);

  int buf = 0;
  for (int kt = 0; kt < 6; ++kt) {
    __syncthreads();
    if (kt < 5) {
      int off = (kt + 1) * 32;
      gld16(descF + agbase + off, &Ab[buf ^ 1][wslot]);
      gld16(w1f + bg0 + off, &Bb[buf ^ 1][wslot]);
      if (t < 128) gld16(w1f + bg1 + off, &Bb[buf ^ 1][2048 + wslot]);
    }
    half8 af = *(const half8*)(&Ab[buf][(wv * 16 + lr) * 32 + quad * 8]);
#pragma unroll
    for (int j = 0; j < 6; ++j) {
      half8 bf = *(const half8*)(&Bb[buf][(j * 16 + lr) * 32 + quad * 8]);
      acc[j] = __builtin_amdgcn_mfma_f32_16x16x32_f16(af, bf, acc[j], 0, 0, 0);
    }
    buf ^= 1;
  }

  _Float16* pp = pacc + (long)(ck * 196 + mt) * 6144;
#pragma unroll
  for (int j = 0; j < 6; ++j)
#pragma unroll
    for (int r = 0; r < 4; ++r)
      pp[(wv * 16 + quad * 4 + r) * 96 + j * 16 + lr] = (_Float16)acc[j][r];
}

// ---------------- kGemm2 v2: reduce(11 pacc)+BN+ReLU -> y tile -> GEMM2 -> softmax ------
// grid = 392 blocks x 256 threads; 32 rows per block; waves = 2(row-half) x 2(col-half).
__global__ __launch_bounds__(256) void kGemm2(
    const _Float16* __restrict__ pacc,
    const float* __restrict__ gamma, const float* __restrict__ beta,
    const float* __restrict__ mean, const float* __restrict__ var,
    const _Float16* __restrict__ w2f, const _Float16* __restrict__ w3f,
    const float* __restrict__ b2, const float* __restrict__ b3,
    _Float16* __restrict__ wtg) {
  __shared__ __align__(16) char smem[24576];
  _Float16* ytF = (_Float16*)smem;        // [0, 6656): 32*104 fp16 (dead after MFMA loop)
  float* wal = (float*)smem;              // [0, 12288): 32*96 f32 (after ytF dead)
  float* wbl = wal + 3072;                // [12288, 24576)
  __shared__ float invv[96], biasv[96];

  const int t = threadIdx.x;
  const int wv = t >> 6, lane = t & 63, quad = lane >> 4, lr = lane & 15;
  const int wr = wv & 1, wc = wv >> 1;
  const long mblk = (long)blockIdx.x * 32;

  if (t < 96) {
    float iv = gamma[t] * rsqrtf(var[t] + 1e-5f);
    invv[t] = iv; biasv[t] = beta[t] - mean[t] * iv;
  }
  __syncthreads();

  // stage: sum 11 split-K slices + BN + ReLU -> ytF [32][104]; 768 quads / 256 threads
#pragma unroll
  for (int i = 0; i < 3; ++i) {
    int q = t + i * 256;                  // 0..767
    int m = q / 24, nq = (q - m * 24) * 4;
    long gbase = (mblk + m) * 96 + nq;
    float s0 = 0.f, s1 = 0.f, s2 = 0.f, s3 = 0.f;
#pragma unroll
    for (int ck = 0; ck < 11; ++ck) {
      half4 v = *(const half4*)(pacc + (long)ck * 1204224 + gbase);
      s0 += (float)v.x; s1 += (float)v.y; s2 += (float)v.z; s3 += (float)v.w;
    }
    half4 o;
    o.x = (_Float16)fmaxf(s0 * invv[nq + 0] + biasv[nq + 0], 0.f);
    o.y = (_Float16)fmaxf(s1 * invv[nq + 1] + biasv[nq + 1], 0.f);
    o.z = (_Float16)fmaxf(s2 * invv[nq + 2] + biasv[nq + 2], 0.f);
    o.w = (_Float16)fmaxf(s3 * invv[nq + 3] + biasv[nq + 3], 0.f);
    *(half4*)(ytF + m * 104 + nq) = o;
  }
  __syncthreads();

  floatx4 aa[3], ab[3];
#pragma unroll
  for (int j = 0; j < 3; ++j) { aa[j] = {0.f,0.f,0.f,0.f}; ab[j] = {0.f,0.f,0.f,0.f}; }
#pragma unroll
  for (int ks = 0; ks < 3; ++ks) {
    half8 af = *(const half8*)(ytF + (wr * 16 + lr) * 104 + ks * 32 + quad * 8);
#pragma unroll
    for (int j = 0; j < 3; ++j) {
      int n = (wc * 3 + j) * 16 + lr;
      int wo = n * 96 + ks * 32 + quad * 8;
      half8 b2v = *(const half8*)(w2f + wo);
      half8 b3v = *(const half8*)(w3f + wo);
      aa[j] = __builtin_amdgcn_mfma_f32_16x16x32_f16(af, b2v, aa[j], 0, 0, 0);
      ab[j] = __builtin_amdgcn_mfma_f32_16x16x32_f16(af, b3v, ab[j], 0, 0, 0);
    }
  }
  __syncthreads();   // ytF dead; smem becomes wal/wbl

#pragma unroll
  for (int j = 0; j < 3; ++j) {
    int n = (wc * 3 + j) * 16 + lr;
    float bb2 = b2[n], bb3 = b3[n];
#pragma unroll
    for (int r = 0; r < 4; ++r) {
      int m = wr * 16 + quad * 4 + r;
      wal[m * 96 + n] = aa[j][r] + bb2;
      wbl[m * 96 + n] = ab[j][r] + bb3;
    }
  }
  __syncthreads();

  // softmax: 32 rows x 64 (g,ns) units = 2048 / 256 threads
#pragma unroll
  for (int it = 0; it < 8; ++it) {
    int u = t + it * 256;
    int m = u >> 6, rest = u & 63;
    int g = rest >> 2, ns = rest & 3;
    int ns1 = ns >> 1, ns2 = ns & 1;
    float la[3], lb[3];
#pragma unroll
    for (int k = 0; k < 3; ++k) {
      la[k] = wal[m * 96 + (g * 3 + k) * 2 + ns1];
      lb[k] = wbl[m * 96 + (g * 3 + k) * 2 + ns2];
    }
    float lg[9], mx = -1e30f;
#pragma unroll
    for (int k1 = 0; k1 < 3; ++k1)
#pragma unroll
      for (int k2 = 0; k2 < 3; ++k2) {
        float v = la[k1] * lb[k2];
        lg[k1 * 3 + k2] = v;
        mx = v > mx ? v : mx;
      }
    float s = 0.f;
#pragma unroll
    for (int k = 0; k < 9; ++k) { lg[k] = __expf(lg[k] - mx); s += lg[k]; }
    float sc = 1.f / (9.f * s);
    _Float16* dst = wtg + (mblk + m) * 576 + g * 36 + ns * 9;
#pragma unroll
    for (int k = 0; k < 9; ++k) dst[k] = (_Float16)(lg[k] * sc);
  }
}

// ---------------- kApply: x + wt -> out ----------
// block = (b, h', wh(2), g(16)): 7168 blocks, 256 threads; 16 channels, 28 w-positions.
__global__ __launch_bounds__(256) void kApply(const float* __restrict__ x,
                                              const _Float16* __restrict__ wt,
                                              float* __restrict__ out) {
  int bid = blockIdx.x;
  int g = bid & 15;
  int wh = (bid >> 4) & 1;
  int h = (bid >> 5) % 56;
  int b = bid / 1792;
  int wbase = wh * 28, cbase = g * 16;

  __shared__ _Float16 xr[9 * 16 * 30];       // [(k2*3+k1)*480 + cl*30 + wc]
  __shared__ __align__(16) float wtb[28 * 36]; // [p*36 + (k1*3+k2)*4 + ns]
  __shared__ float ob[32 * 57];              // [(cl*2+ns1)*57 + p*2+ns2]

  int t = threadIdx.x;

  // fill xr: 144 rows x 30 cols; fully-batched loads
  {
    int wc = t & 31;
    int r0 = t >> 5;                    // 0..7
    int wr = wbase + wc - 1;
    bool wok = (wc < 30) & (wr >= 0) & (wr < 56);
    const long xb0 = ((long)b * 256 + cbase) * 3136;
    float vals[18];
#pragma unroll
    for (int i = 0; i < 18; ++i) {
      int row = r0 + i * 8;             // 0..143
      int kk = row >> 4, cl = row & 15;
      int k2 = kk / 3, k1 = kk - 3 * k2;
      int gr = (k2 * 56 + h) / 3 + k1 - 1;
      float v = 0.f;
      if (wok && gr >= 0 && gr < 56)
        v = x[xb0 + (long)cl * 3136 + gr * 56 + wr];
      vals[i] = v;
    }
#pragma unroll
    for (int i = 0; i < 18; ++i) {
      int row = r0 + i * 8;
      if (wc < 30) xr[row * 30 + wc] = (_Float16)vals[i];
    }
  }
  // wt -> wtb: wtb[p*36 + kk*4 + ns] = wt[(m0+p)*576 + g*36 + ns*9 + kk]
  {
    long m0 = ((long)(b * 56 + h)) * 56 + wbase;
    float vals[4];
#pragma unroll
    for (int i = 0; i < 4; ++i) {
      int idx = t + i * 256;
      if (idx < 1008) {
        int p = idx / 36, r36 = idx - p * 36;
        int kk = r36 >> 2, ns = r36 & 3;
        vals[i] = (float)wt[(m0 + p) * 576 + g * 36 + ns * 9 + kk];
      }
    }
#pragma unroll
    for (int i = 0; i < 4; ++i) {
      int idx = t + i * 256;
      if (idx < 1008) wtb[idx] = vals[i];
    }
  }
  __syncthreads();

  // compute: thread owns (cl, p); 4 ns accumulators; float4 weight reads
  {
    int j2r[3];
#pragma unroll
    for (int k2 = 0; k2 < 3; ++k2) j2r[k2] = (k2 * 56 + h) % 3;
#pragma unroll
    for (int i = 0; i < 2; ++i) {
      int idx = i * 256 + t;
      int cl = idx & 15;
      int p = idx >> 4;                 // 0..31
      if (p < 28) {
        float a0 = 0.f, a1 = 0.f, a2 = 0.f, a3 = 0.f;
#pragma unroll
        for (int k1 = 0; k1 < 3; ++k1)
#pragma unroll
          for (int k2 = 0; k2 < 3; ++k2) {
            float xv = (float)xr[(k2 * 3 + k1) * 480 + cl * 30 + p + j2r[k2]];
            float4 wv = *(const float4*)&wtb[p * 36 + (k1 * 3 + k2) * 4];
            a0 += xv * wv.x; a1 += xv * wv.y; a2 += xv * wv.z; a3 += xv * wv.w;
          }
        int ob0 = cl * 114 + p * 2;
        ob[ob0] = a0;
        ob[ob0 + 1] = a1;
        ob[ob0 + 57] = a2;
        ob[ob0 + 58] = a3;
      }
    }
  }
  __syncthreads();

  // writeout: 32 rows x 56 cols, coalesced
  {
    int wo = t & 63;
    int r0 = t >> 6;                    // 0..3
    const long obase = (((long)b * 256 + cbase) * 112 + 2 * h) * 112 + wh * 56;
#pragma unroll
    for (int i = 0; i < 8; ++i) {
      int row = r0 + i * 4;             // 0..31
      if (wo < 56) {
        int cli = row >> 1, n1 = row & 1;
        out[obase + cli * 12544 + n1 * 112 + wo] = ob[row * 57 + wo];
      }
    }
  }
}

extern "C" void kernel_launch(void* const* d_in, const int* in_sizes, int n_in,
                              void* d_out, int out_size, void* d_ws, size_t ws_size,
                              hipStream_t stream) {
  const float* x = (const float*)d_in[0];
  const float* w1 = (const float*)d_in[1];
  const float* gamma = (const float*)d_in[2];
  const float* beta = (const float*)d_in[3];
  const float* mean = (const float*)d_in[4];
  const float* var = (const float*)d_in[5];
  const float* w2 = (const float*)d_in[6];
  const float* b2 = (const float*)d_in[7];
  const float* w3 = (const float*)d_in[8];
  const float* b3 = (const float*)d_in[9];
  float* out = (float*)d_out;

  // workspace layout (bytes), total ~94.4 MB:
  //   w1f fp16:   [0, 405504)
  //   w2f fp16:   [405504, 423936)
  //   w3f fp16:   [423936, 442368)
  //   wtg fp16:   [442368, 14893056)
  //   descF fp16: [14893056, 67878912)
  //   pacc fp16:  [67878912, 94371840)   (11 split-K slices)
  _Float16* w1f = (_Float16*)d_ws;
  _Float16* w2f = w1f + 202752;
  _Float16* w3f = w2f + 9216;
  _Float16* wtg = (_Float16*)((char*)d_ws + 442368);
  _Float16* descF = (_Float16*)((char*)d_ws + 14893056);
  _Float16* pacc = (_Float16*)((char*)d_ws + 67878912);

  hipLaunchKernelGGL(kDescC, dim3(4448), dim3(256), 0, stream,
                     x, w1, w2, w3, descF, w1f, w2f, w3f);
  hipLaunchKernelGGL(kGemm1, dim3(2156), dim3(256), 0, stream, descF, w1f, pacc);
  hipLaunchKernelGGL(kGemm2, dim3(392), dim3(256), 0, stream,
                     pacc, gamma, beta, mean, var, w2f, w3f, b2, b3, wtg);
  hipLaunchKernelGGL(kApply, dim3(7168), dim3(256), 0, stream, x, wtg, out);
}

// Round 8
// 155.945 us; speedup vs baseline: 1.5072x; 1.1712x over previous
//
#include <hip/hip_runtime.h>

typedef __attribute__((ext_vector_type(8))) _Float16 half8;
typedef __attribute__((ext_vector_type(4))) _Float16 half4;
typedef __attribute__((ext_vector_type(4))) float floatx4;

// async global->LDS DMA, 16B per lane; lds must be wave-uniform base (+lane*16 implicit)
__device__ inline void gld16(const _Float16* g, _Float16* lds) {
  __builtin_amdgcn_global_load_lds(
      (const __attribute__((address_space(1))) unsigned int*)g,
      (__attribute__((address_space(3))) unsigned int*)lds, 16, 0, 0);
}

// ---------------- kDescC: descriptor builder, branch-free fill ----------------
// blocks [0,3584): (g 16) x (h 56) x (b 4), 256 threads.
// blocks [3584,4448): fp32->fp16 weight casts.
// tap(k1,k2) at (h',w') = x[row=(k2*56+h')/3+k1-1, col=w'+(k2*56+h')%3-1], zero-pad.
__global__ __launch_bounds__(256) void kDescC(const float* __restrict__ x,
                                              const float* __restrict__ w1,
                                              const float* __restrict__ w2,
                                              const float* __restrict__ w3,
                                              _Float16* __restrict__ descF,
                                              _Float16* __restrict__ w1f,
                                              _Float16* __restrict__ w2f,
                                              _Float16* __restrict__ w3f) {
  const int bid = blockIdx.x;
  const int t = threadIdx.x;

  if (bid >= 3584) {                    // ---- weight-cast blocks ----
    int i = (bid - 3584) * 256 + t;
    if (i < 202752) w1f[i] = (_Float16)w1[i];
    else if (i < 211968) w2f[i - 202752] = (_Float16)w2[i - 202752];
    else if (i < 221184) w3f[i - 211968] = (_Float16)w3[i - 211968];
    return;
  }

  int g = bid & 15;
  int h = (bid >> 4) % 56;
  int b = bid / 896;

  // xb row stride = 72 halves (144 B). chunk c (8 halves) stored at c ^ (kk&7).
  __shared__ __align__(16) _Float16 xb[144 * 72];   // 20736 B
  __shared__ __align__(16) int tOf[132][4];         // enc = row*144 | key (key=(row>>4)&7)

  // ---- tap-offset table (132 threads) ----
  if (t < 132) {
    int dl = t;
    int r0, r1, r2, r3;
    if (dl < 36) {                       // x1: max over 4 sub-channels
      int a3 = dl / 9, rem = dl % 9, k1 = rem / 3, k2 = rem % 3;
      int br = (k2 * 3 + k1) * 16 + a3;
      r0 = br; r1 = br + 4; r2 = br + 8; r3 = br + 12;
    } else if (dl < 84) {                // x2: max over k1
      int u = dl - 36, gc = u / 3, k2 = u % 3;
      r0 = (k2 * 3 + 0) * 16 + gc;
      r1 = (k2 * 3 + 1) * 16 + gc;
      r2 = (k2 * 3 + 2) * 16 + gc;
      r3 = r0;
    } else {                             // x3: max over k2
      int u = dl - 84, gc = u / 3, k1 = u % 3;
      r0 = (0 + k1) * 16 + gc;
      r1 = (3 + k1) * 16 + gc;
      r2 = (6 + k1) * 16 + gc;
      r3 = r0;
    }
    tOf[dl][0] = r0 * 144 + ((r0 >> 4) & 7);
    tOf[dl][1] = r1 * 144 + ((r1 >> 4) & 7);
    tOf[dl][2] = r2 * 144 + ((r2 >> 4) & 7);
    tOf[dl][3] = r3 * 144 + ((r3 >> 4) & 7);
  }

  // ---- fill xb: branch-free. interior 1728 units (c4=1..12) + boundary 288 units ----
  {
    const long xp = ((long)b * 256 + g * 16) * 3136;
    // interior: unconditional dwordx4 from row-clamped address; cols always in [3,52]
#pragma unroll
    for (int i = 0; i < 7; ++i) {
      int idx = t + i * 256;
      if (idx < 1728) {
        int r = (idx * 2731) >> 15;     // idx/12 (exact for idx<1792)
        int c4 = idx - r * 12 + 1;      // 1..12
        int kk = r >> 4, ch = r & 15;
        int k2 = (kk >= 6) ? 2 : (kk >= 3 ? 1 : 0);
        int k1 = kk - 3 * k2;
        int t2 = k2 * 56 + h;
        int q3 = (t2 * 683) >> 11;      // t2/3 (exact for t2<168)
        int s = t2 - q3 * 3;
        int gr = q3 + k1 - 1;
        int grc = min(max(gr, 0), 55);
        const float* rp = x + xp + (long)ch * 3136 + (long)grc * 56 + (s - 1) + c4 * 4;
        float fv[4];
        __builtin_memcpy(fv, rp, 16);
        bool rok = (unsigned)gr < 56u;
        half4 hv;
        hv[0] = (_Float16)(rok ? fv[0] : 0.f);
        hv[1] = (_Float16)(rok ? fv[1] : 0.f);
        hv[2] = (_Float16)(rok ? fv[2] : 0.f);
        hv[3] = (_Float16)(rok ? fv[3] : 0.f);
        int chunk = (c4 >> 1) ^ (kk & 7);
        *(half4*)((char*)xb + r * 144 + chunk * 16 + (c4 & 1) * 8) = hv;
      }
    }
    // boundary: c4 in {0,13}; clamped scalar loads + selects, no branches
#pragma unroll
    for (int i = 0; i < 2; ++i) {
      int idx = t + i * 256;
      if (idx < 288) {
        int r = idx >> 1;
        int c4 = (idx & 1) ? 13 : 0;
        int kk = r >> 4, ch = r & 15;
        int k2 = (kk >= 6) ? 2 : (kk >= 3 ? 1 : 0);
        int k1 = kk - 3 * k2;
        int t2 = k2 * 56 + h;
        int q3 = (t2 * 683) >> 11;
        int s = t2 - q3 * 3;
        int gr = q3 + k1 - 1;
        int grc = min(max(gr, 0), 55);
        bool rok = (unsigned)gr < 56u;
        const float* rp = x + xp + (long)ch * 3136 + (long)grc * 56;
        half4 hv;
#pragma unroll
        for (int e = 0; e < 4; ++e) {
          int cg = c4 * 4 + e + s - 1;
          int cgc = min(max(cg, 0), 55);
          float v = rp[cgc];
          hv[e] = (_Float16)((rok & ((unsigned)cg < 56u)) ? v : 0.f);
        }
        int chunk = (c4 >> 1) ^ (kk & 7);
        *(half4*)((char*)xb + r * 144 + chunk * 16 + (c4 & 1) * 8) = hv;
      }
    }
  }
  __syncthreads();

  // ---- compute + transpose + store: 231 units = (pc 0..6) x (dlc 0..32) ----
  const long m00 = ((long)(b * 56 + h)) * 56;
  if (t < 231) {
    int pc = t / 33, dlc = t - pc * 33;
    int dl0 = dlc * 4;
    half8 r8s[4];
    const char* xbb = (const char*)xb;
#pragma unroll
    for (int i = 0; i < 4; ++i) {
      const int4 of = *(const int4*)tOf[dl0 + i];
      half8 v0 = *(const half8*)(xbb + (of.x & ~15) + ((pc ^ (of.x & 15)) << 4));
      half8 v1 = *(const half8*)(xbb + (of.y & ~15) + ((pc ^ (of.y & 15)) << 4));
      half8 v2 = *(const half8*)(xbb + (of.z & ~15) + ((pc ^ (of.z & 15)) << 4));
      half8 v3 = *(const half8*)(xbb + (of.w & ~15) + ((pc ^ (of.w & 15)) << 4));
      half8 a = __builtin_elementwise_max(v0, v1);
      half8 c = __builtin_elementwise_max(v2, v3);
      r8s[i] = __builtin_elementwise_max(a, c);
    }
    int dg0 = (dlc < 9)  ? (g * 36 + dl0)
            : (dlc < 21) ? (576 + g * 48 + (dl0 - 36))
                         : (1344 + g * 48 + (dl0 - 84));
    _Float16* dp = descF + (m00 + pc * 8) * 2112 + dg0;
#pragma unroll
    for (int e = 0; e < 8; ++e) {
      half4 o;
      o[0] = r8s[0][e]; o[1] = r8s[1][e]; o[2] = r8s[2][e]; o[3] = r8s[3][e];
      *(half4*)(dp + (long)e * 2112) = o;   // 8B store, 8B-aligned
    }
  }
}

// ---------------- kGemm1: split-K partial GEMM, LDS-staged via global_load_lds ----------
// grid = 196 Mtiles x 11 K-chunks = 2156 blocks; 256 threads; M=64, N=96, K-chunk=192, BK=32.
__global__ __launch_bounds__(256) void kGemm1(
    const _Float16* __restrict__ descF, const _Float16* __restrict__ w1f,
    _Float16* __restrict__ pacc) {
  __shared__ _Float16 Ab[2][64 * 32];   // [row*32 + c*8]
  __shared__ _Float16 Bb[2][96 * 32];   // [n*32 + c*8]
  const int t = threadIdx.x;
  const int wv = t >> 6, lane = t & 63, quad = lane >> 4, lr = lane & 15;
  const int mt = blockIdx.x / 11, ck = blockIdx.x % 11;
  const long mblk = (long)mt * 64;

  const long agbase = (mblk + (t >> 2)) * 2112 + ck * 192 + (t & 3) * 8;
  const long bg0 = (long)(t >> 2) * 2112 + ck * 192 + (t & 3) * 8;
  const long bg1 = (long)((256 + t) >> 2) * 2112 + ck * 192 + (t & 3) * 8;
  const int wslot = (t >> 6) * 512;     // wave-uniform LDS base (halves)

  floatx4 acc[6];
#pragma unroll
  for (int j = 0; j < 6; ++j) acc[j] = {0.f, 0.f, 0.f, 0.f};

  gld16(descF + agbase, &Ab[0][wslot]);
  gld16(w1f + bg0, &Bb[0][wslot]);
  if (t < 128) gld16(w1f + bg1, &Bb[0][2048 + wslot]);

  int buf = 0;
  for (int kt = 0; kt < 6; ++kt) {
    __syncthreads();
    if (kt < 5) {
      int off = (kt + 1) * 32;
      gld16(descF + agbase + off, &Ab[buf ^ 1][wslot]);
      gld16(w1f + bg0 + off, &Bb[buf ^ 1][wslot]);
      if (t < 128) gld16(w1f + bg1 + off, &Bb[buf ^ 1][2048 + wslot]);
    }
    half8 af = *(const half8*)(&Ab[buf][(wv * 16 + lr) * 32 + quad * 8]);
#pragma unroll
    for (int j = 0; j < 6; ++j) {
      half8 bf = *(const half8*)(&Bb[buf][(j * 16 + lr) * 32 + quad * 8]);
      acc[j] = __builtin_amdgcn_mfma_f32_16x16x32_f16(af, bf, acc[j], 0, 0, 0);
    }
    buf ^= 1;
  }

  _Float16* pp = pacc + (long)(ck * 196 + mt) * 6144;
#pragma unroll
  for (int j = 0; j < 6; ++j)
#pragma unroll
    for (int r = 0; r < 4; ++r)
      pp[(wv * 16 + quad * 4 + r) * 96 + j * 16 + lr] = (_Float16)acc[j][r];
}

// ---------------- kGemm2 v2: reduce(11 pacc)+BN+ReLU -> y tile -> GEMM2 -> softmax ------
// grid = 392 blocks x 256 threads; 32 rows per block; waves = 2(row-half) x 2(col-half).
__global__ __launch_bounds__(256) void kGemm2(
    const _Float16* __restrict__ pacc,
    const float* __restrict__ gamma, const float* __restrict__ beta,
    const float* __restrict__ mean, const float* __restrict__ var,
    const _Float16* __restrict__ w2f, const _Float16* __restrict__ w3f,
    const float* __restrict__ b2, const float* __restrict__ b3,
    _Float16* __restrict__ wtg) {
  __shared__ __align__(16) char smem[24576];
  _Float16* ytF = (_Float16*)smem;        // [0, 6656): 32*104 fp16 (dead after MFMA loop)
  float* wal = (float*)smem;              // [0, 12288): 32*96 f32 (after ytF dead)
  float* wbl = wal + 3072;                // [12288, 24576)
  __shared__ float invv[96], biasv[96];

  const int t = threadIdx.x;
  const int wv = t >> 6, lane = t & 63, quad = lane >> 4, lr = lane & 15;
  const int wr = wv & 1, wc = wv >> 1;
  const long mblk = (long)blockIdx.x * 32;

  if (t < 96) {
    float iv = gamma[t] * rsqrtf(var[t] + 1e-5f);
    invv[t] = iv; biasv[t] = beta[t] - mean[t] * iv;
  }
  __syncthreads();

  // stage: sum 11 split-K slices + BN + ReLU -> ytF [32][104]; 768 quads / 256 threads
#pragma unroll
  for (int i = 0; i < 3; ++i) {
    int q = t + i * 256;                  // 0..767
    int m = q / 24, nq = (q - m * 24) * 4;
    long gbase = (mblk + m) * 96 + nq;
    float s0 = 0.f, s1 = 0.f, s2 = 0.f, s3 = 0.f;
#pragma unroll
    for (int ck = 0; ck < 11; ++ck) {
      half4 v = *(const half4*)(pacc + (long)ck * 1204224 + gbase);
      s0 += (float)v.x; s1 += (float)v.y; s2 += (float)v.z; s3 += (float)v.w;
    }
    half4 o;
    o.x = (_Float16)fmaxf(s0 * invv[nq + 0] + biasv[nq + 0], 0.f);
    o.y = (_Float16)fmaxf(s1 * invv[nq + 1] + biasv[nq + 1], 0.f);
    o.z = (_Float16)fmaxf(s2 * invv[nq + 2] + biasv[nq + 2], 0.f);
    o.w = (_Float16)fmaxf(s3 * invv[nq + 3] + biasv[nq + 3], 0.f);
    *(half4*)(ytF + m * 104 + nq) = o;
  }
  __syncthreads();

  floatx4 aa[3], ab[3];
#pragma unroll
  for (int j = 0; j < 3; ++j) { aa[j] = {0.f,0.f,0.f,0.f}; ab[j] = {0.f,0.f,0.f,0.f}; }
#pragma unroll
  for (int ks = 0; ks < 3; ++ks) {
    half8 af = *(const half8*)(ytF + (wr * 16 + lr) * 104 + ks * 32 + quad * 8);
#pragma unroll
    for (int j = 0; j < 3; ++j) {
      int n = (wc * 3 + j) * 16 + lr;
      int wo = n * 96 + ks * 32 + quad * 8;
      half8 b2v = *(const half8*)(w2f + wo);
      half8 b3v = *(const half8*)(w3f + wo);
      aa[j] = __builtin_amdgcn_mfma_f32_16x16x32_f16(af, b2v, aa[j], 0, 0, 0);
      ab[j] = __builtin_amdgcn_mfma_f32_16x16x32_f16(af, b3v, ab[j], 0, 0, 0);
    }
  }
  __syncthreads();   // ytF dead; smem becomes wal/wbl

#pragma unroll
  for (int j = 0; j < 3; ++j) {
    int n = (wc * 3 + j) * 16 + lr;
    float bb2 = b2[n], bb3 = b3[n];
#pragma unroll
    for (int r = 0; r < 4; ++r) {
      int m = wr * 16 + quad * 4 + r;
      wal[m * 96 + n] = aa[j][r] + bb2;
      wbl[m * 96 + n] = ab[j][r] + bb3;
    }
  }
  __syncthreads();

  // softmax: 32 rows x 64 (g,ns) units = 2048 / 256 threads
#pragma unroll
  for (int it = 0; it < 8; ++it) {
    int u = t + it * 256;
    int m = u >> 6, rest = u & 63;
    int g = rest >> 2, ns = rest & 3;
    int ns1 = ns >> 1, ns2 = ns & 1;
    float la[3], lb[3];
#pragma unroll
    for (int k = 0; k < 3; ++k) {
      la[k] = wal[m * 96 + (g * 3 + k) * 2 + ns1];
      lb[k] = wbl[m * 96 + (g * 3 + k) * 2 + ns2];
    }
    float lg[9], mx = -1e30f;
#pragma unroll
    for (int k1 = 0; k1 < 3; ++k1)
#pragma unroll
      for (int k2 = 0; k2 < 3; ++k2) {
        float v = la[k1] * lb[k2];
        lg[k1 * 3 + k2] = v;
        mx = v > mx ? v : mx;
      }
    float s = 0.f;
#pragma unroll
    for (int k = 0; k < 9; ++k) { lg[k] = __expf(lg[k] - mx); s += lg[k]; }
    float sc = 1.f / (9.f * s);
    _Float16* dst = wtg + (mblk + m) * 576 + g * 36 + ns * 9;
#pragma unroll
    for (int k = 0; k < 9; ++k) dst[k] = (_Float16)(lg[k] * sc);
  }
}

// ---------------- kApply: x + wt -> out; branch-free fill ----------
// block = (b, h', wh(2), g(16)): 7168 blocks, 256 threads; 16 channels, 28 w-positions.
__global__ __launch_bounds__(256) void kApply(const float* __restrict__ x,
                                              const _Float16* __restrict__ wt,
                                              float* __restrict__ out) {
  int bid = blockIdx.x;
  int g = bid & 15;
  int wh = (bid >> 4) & 1;
  int h = (bid >> 5) % 56;
  int b = bid / 1792;
  int wbase = wh * 28, cbase = g * 16;

  __shared__ _Float16 xr[9 * 16 * 30];       // [(k2*3+k1)*480 + cl*30 + wc]
  __shared__ __align__(16) float wtb[28 * 36]; // [p*36 + (k1*3+k2)*4 + ns]
  __shared__ float ob[32 * 57];              // [(cl*2+ns1)*57 + p*2+ns2]

  int t = threadIdx.x;

  // fill xr: 144 rows x 30 cols; clamped unconditional loads + selects (no branches)
  {
    int wc = t & 31;
    int r0 = t >> 5;                    // 0..7
    int wr = wbase + wc - 1;
    int wrc = min(max(wr, 0), 55);
    bool cok = (wc < 30) & ((unsigned)wr < 56u);
    const long xb0 = ((long)b * 256 + cbase) * 3136;
    float vals[18];
#pragma unroll
    for (int i = 0; i < 18; ++i) {
      int row = r0 + i * 8;             // 0..143
      int kk = row >> 4, cl = row & 15;
      int k2 = (kk >= 6) ? 2 : (kk >= 3 ? 1 : 0);
      int k1 = kk - 3 * k2;
      int t2 = k2 * 56 + h;
      int q3 = (t2 * 683) >> 11;        // t2/3
      int gr = q3 + k1 - 1;
      int grc = min(max(gr, 0), 55);
      float v = x[xb0 + (long)cl * 3136 + (long)grc * 56 + wrc];
      vals[i] = (cok & ((unsigned)gr < 56u)) ? v : 0.f;
    }
#pragma unroll
    for (int i = 0; i < 18; ++i) {
      int row = r0 + i * 8;
      if (wc < 30) xr[row * 30 + wc] = (_Float16)vals[i];
    }
  }
  // wt -> wtb: wtb[p*36 + kk*4 + ns] = wt[(m0+p)*576 + g*36 + ns*9 + kk]
  {
    long m0 = ((long)(b * 56 + h)) * 56 + wbase;
    float vals[4];
#pragma unroll
    for (int i = 0; i < 4; ++i) {
      int idx = t + i * 256;
      if (idx < 1008) {
        int p = idx / 36, r36 = idx - p * 36;
        int kk = r36 >> 2, ns = r36 & 3;
        vals[i] = (float)wt[(m0 + p) * 576 + g * 36 + ns * 9 + kk];
      }
    }
#pragma unroll
    for (int i = 0; i < 4; ++i) {
      int idx = t + i * 256;
      if (idx < 1008) wtb[idx] = vals[i];
    }
  }
  __syncthreads();

  // compute: thread owns (cl, p); 4 ns accumulators; float4 weight reads
  {
    int j2r[3];
#pragma unroll
    for (int k2 = 0; k2 < 3; ++k2) j2r[k2] = (k2 * 56 + h) % 3;
#pragma unroll
    for (int i = 0; i < 2; ++i) {
      int idx = i * 256 + t;
      int cl = idx & 15;
      int p = idx >> 4;                 // 0..31
      if (p < 28) {
        float a0 = 0.f, a1 = 0.f, a2 = 0.f, a3 = 0.f;
#pragma unroll
        for (int k1 = 0; k1 < 3; ++k1)
#pragma unroll
          for (int k2 = 0; k2 < 3; ++k2) {
            float xv = (float)xr[(k2 * 3 + k1) * 480 + cl * 30 + p + j2r[k2]];
            float4 wv = *(const float4*)&wtb[p * 36 + (k1 * 3 + k2) * 4];
            a0 += xv * wv.x; a1 += xv * wv.y; a2 += xv * wv.z; a3 += xv * wv.w;
          }
        int ob0 = cl * 114 + p * 2;
        ob[ob0] = a0;
        ob[ob0 + 1] = a1;
        ob[ob0 + 57] = a2;
        ob[ob0 + 58] = a3;
      }
    }
  }
  __syncthreads();

  // writeout: 32 rows x 56 cols, coalesced
  {
    int wo = t & 63;
    int r0 = t >> 6;                    // 0..3
    const long obase = (((long)b * 256 + cbase) * 112 + 2 * h) * 112 + wh * 56;
#pragma unroll
    for (int i = 0; i < 8; ++i) {
      int row = r0 + i * 4;             // 0..31
      if (wo < 56) {
        int cli = row >> 1, n1 = row & 1;
        out[obase + cli * 12544 + n1 * 112 + wo] = ob[row * 57 + wo];
      }
    }
  }
}

extern "C" void kernel_launch(void* const* d_in, const int* in_sizes, int n_in,
                              void* d_out, int out_size, void* d_ws, size_t ws_size,
                              hipStream_t stream) {
  const float* x = (const float*)d_in[0];
  const float* w1 = (const float*)d_in[1];
  const float* gamma = (const float*)d_in[2];
  const float* beta = (const float*)d_in[3];
  const float* mean = (const float*)d_in[4];
  const float* var = (const float*)d_in[5];
  const float* w2 = (const float*)d_in[6];
  const float* b2 = (const float*)d_in[7];
  const float* w3 = (const float*)d_in[8];
  const float* b3 = (const float*)d_in[9];
  float* out = (float*)d_out;

  // workspace layout (bytes), total ~94.4 MB:
  //   w1f fp16:   [0, 405504)
  //   w2f fp16:   [405504, 423936)
  //   w3f fp16:   [423936, 442368)
  //   wtg fp16:   [442368, 14893056)
  //   descF fp16: [14893056, 67878912)
  //   pacc fp16:  [67878912, 94371840)   (11 split-K slices)
  _Float16* w1f = (_Float16*)d_ws;
  _Float16* w2f = w1f + 202752;
  _Float16* w3f = w2f + 9216;
  _Float16* wtg = (_Float16*)((char*)d_ws + 442368);
  _Float16* descF = (_Float16*)((char*)d_ws + 14893056);
  _Float16* pacc = (_Float16*)((char*)d_ws + 67878912);

  hipLaunchKernelGGL(kDescC, dim3(4448), dim3(256), 0, stream,
                     x, w1, w2, w3, descF, w1f, w2f, w3f);
  hipLaunchKernelGGL(kGemm1, dim3(2156), dim3(256), 0, stream, descF, w1f, pacc);
  hipLaunchKernelGGL(kGemm2, dim3(392), dim3(256), 0, stream,
                     pacc, gamma, beta, mean, var, w2f, w3f, b2, b3, wtg);
  hipLaunchKernelGGL(kApply, dim3(7168), dim3(256), 0, stream, x, wtg, out);
}

// Round 9
// 152.069 us; speedup vs baseline: 1.5456x; 1.0255x over previous
//
#include <hip/hip_runtime.h>

typedef __attribute__((ext_vector_type(8))) _Float16 half8;
typedef __attribute__((ext_vector_type(4))) _Float16 half4;
typedef __attribute__((ext_vector_type(4))) float floatx4;

// async global->LDS DMA, 16B per lane; lds must be wave-uniform base (+lane*16 implicit)
__device__ inline void gld16(const _Float16* g, _Float16* lds) {
  __builtin_amdgcn_global_load_lds(
      (const __attribute__((address_space(1))) unsigned int*)g,
      (__attribute__((address_space(3))) unsigned int*)lds, 16, 0, 0);
}

// ---------------- kDescC: descriptor builder, branch-free fill ----------------
// blocks [0,3584): (g 16) x (h 56) x (b 4), 256 threads.
// blocks [3584,4448): fp32->fp16 weight casts.
// tap(k1,k2) at (h',w') = x[row=(k2*56+h')/3+k1-1, col=w'+(k2*56+h')%3-1], zero-pad.
__global__ __launch_bounds__(256) void kDescC(const float* __restrict__ x,
                                              const float* __restrict__ w1,
                                              const float* __restrict__ w2,
                                              const float* __restrict__ w3,
                                              _Float16* __restrict__ descF,
                                              _Float16* __restrict__ w1f,
                                              _Float16* __restrict__ w2f,
                                              _Float16* __restrict__ w3f) {
  const int bid = blockIdx.x;
  const int t = threadIdx.x;

  if (bid >= 3584) {                    // ---- weight-cast blocks ----
    int i = (bid - 3584) * 256 + t;
    if (i < 202752) w1f[i] = (_Float16)w1[i];
    else if (i < 211968) w2f[i - 202752] = (_Float16)w2[i - 202752];
    else if (i < 221184) w3f[i - 211968] = (_Float16)w3[i - 211968];
    return;
  }

  int g = bid & 15;
  int h = (bid >> 4) % 56;
  int b = bid / 896;

  // xb row stride = 72 halves (144 B). chunk c (8 halves) stored at c ^ (kk&7).
  __shared__ __align__(16) _Float16 xb[144 * 72];   // 20736 B
  __shared__ __align__(16) int tOf[132][4];         // enc = row*144 | key (key=(row>>4)&7)

  // ---- tap-offset table (132 threads) ----
  if (t < 132) {
    int dl = t;
    int r0, r1, r2, r3;
    if (dl < 36) {                       // x1: max over 4 sub-channels
      int a3 = dl / 9, rem = dl % 9, k1 = rem / 3, k2 = rem % 3;
      int br = (k2 * 3 + k1) * 16 + a3;
      r0 = br; r1 = br + 4; r2 = br + 8; r3 = br + 12;
    } else if (dl < 84) {                // x2: max over k1
      int u = dl - 36, gc = u / 3, k2 = u % 3;
      r0 = (k2 * 3 + 0) * 16 + gc;
      r1 = (k2 * 3 + 1) * 16 + gc;
      r2 = (k2 * 3 + 2) * 16 + gc;
      r3 = r0;
    } else {                             // x3: max over k2
      int u = dl - 84, gc = u / 3, k1 = u % 3;
      r0 = (0 + k1) * 16 + gc;
      r1 = (3 + k1) * 16 + gc;
      r2 = (6 + k1) * 16 + gc;
      r3 = r0;
    }
    tOf[dl][0] = r0 * 144 + ((r0 >> 4) & 7);
    tOf[dl][1] = r1 * 144 + ((r1 >> 4) & 7);
    tOf[dl][2] = r2 * 144 + ((r2 >> 4) & 7);
    tOf[dl][3] = r3 * 144 + ((r3 >> 4) & 7);
  }

  // ---- fill xb: branch-free. interior 1728 units (c4=1..12) + boundary 288 units ----
  {
    const long xp = ((long)b * 256 + g * 16) * 3136;
    // interior: unconditional dwordx4 from row-clamped address; cols always in [3,52]
#pragma unroll
    for (int i = 0; i < 7; ++i) {
      int idx = t + i * 256;
      if (idx < 1728) {
        int r = (idx * 2731) >> 15;     // idx/12 (exact for idx<1792)
        int c4 = idx - r * 12 + 1;      // 1..12
        int kk = r >> 4, ch = r & 15;
        int k2 = (kk >= 6) ? 2 : (kk >= 3 ? 1 : 0);
        int k1 = kk - 3 * k2;
        int t2 = k2 * 56 + h;
        int q3 = (t2 * 683) >> 11;      // t2/3 (exact for t2<168)
        int s = t2 - q3 * 3;
        int gr = q3 + k1 - 1;
        int grc = min(max(gr, 0), 55);
        const float* rp = x + xp + (long)ch * 3136 + (long)grc * 56 + (s - 1) + c4 * 4;
        float fv[4];
        __builtin_memcpy(fv, rp, 16);
        bool rok = (unsigned)gr < 56u;
        half4 hv;
        hv[0] = (_Float16)(rok ? fv[0] : 0.f);
        hv[1] = (_Float16)(rok ? fv[1] : 0.f);
        hv[2] = (_Float16)(rok ? fv[2] : 0.f);
        hv[3] = (_Float16)(rok ? fv[3] : 0.f);
        int chunk = (c4 >> 1) ^ (kk & 7);
        *(half4*)((char*)xb + r * 144 + chunk * 16 + (c4 & 1) * 8) = hv;
      }
    }
    // boundary: c4 in {0,13}; clamped scalar loads + selects, no branches
#pragma unroll
    for (int i = 0; i < 2; ++i) {
      int idx = t + i * 256;
      if (idx < 288) {
        int r = idx >> 1;
        int c4 = (idx & 1) ? 13 : 0;
        int kk = r >> 4, ch = r & 15;
        int k2 = (kk >= 6) ? 2 : (kk >= 3 ? 1 : 0);
        int k1 = kk - 3 * k2;
        int t2 = k2 * 56 + h;
        int q3 = (t2 * 683) >> 11;
        int s = t2 - q3 * 3;
        int gr = q3 + k1 - 1;
        int grc = min(max(gr, 0), 55);
        bool rok = (unsigned)gr < 56u;
        const float* rp = x + xp + (long)ch * 3136 + (long)grc * 56;
        half4 hv;
#pragma unroll
        for (int e = 0; e < 4; ++e) {
          int cg = c4 * 4 + e + s - 1;
          int cgc = min(max(cg, 0), 55);
          float v = rp[cgc];
          hv[e] = (_Float16)((rok & ((unsigned)cg < 56u)) ? v : 0.f);
        }
        int chunk = (c4 >> 1) ^ (kk & 7);
        *(half4*)((char*)xb + r * 144 + chunk * 16 + (c4 & 1) * 8) = hv;
      }
    }
  }
  __syncthreads();

  // ---- compute + transpose + store: 231 units = (pc 0..6) x (dlc 0..32) ----
  const long m00 = ((long)(b * 56 + h)) * 56;
  if (t < 231) {
    int pc = t / 33, dlc = t - pc * 33;
    int dl0 = dlc * 4;
    half8 r8s[4];
    const char* xbb = (const char*)xb;
#pragma unroll
    for (int i = 0; i < 4; ++i) {
      const int4 of = *(const int4*)tOf[dl0 + i];
      half8 v0 = *(const half8*)(xbb + (of.x & ~15) + ((pc ^ (of.x & 15)) << 4));
      half8 v1 = *(const half8*)(xbb + (of.y & ~15) + ((pc ^ (of.y & 15)) << 4));
      half8 v2 = *(const half8*)(xbb + (of.z & ~15) + ((pc ^ (of.z & 15)) << 4));
      half8 v3 = *(const half8*)(xbb + (of.w & ~15) + ((pc ^ (of.w & 15)) << 4));
      half8 a = __builtin_elementwise_max(v0, v1);
      half8 c = __builtin_elementwise_max(v2, v3);
      r8s[i] = __builtin_elementwise_max(a, c);
    }
    int dg0 = (dlc < 9)  ? (g * 36 + dl0)
            : (dlc < 21) ? (576 + g * 48 + (dl0 - 36))
                         : (1344 + g * 48 + (dl0 - 84));
    _Float16* dp = descF + (m00 + pc * 8) * 2112 + dg0;
#pragma unroll
    for (int e = 0; e < 8; ++e) {
      half4 o;
      o[0] = r8s[0][e]; o[1] = r8s[1][e]; o[2] = r8s[2][e]; o[3] = r8s[3][e];
      *(half4*)(dp + (long)e * 2112) = o;   // 8B store, 8B-aligned
    }
  }
}

// ---------------- kGemm1: split-K partial GEMM, LDS-staged via global_load_lds ----------
// grid = 196 Mtiles x 6 K-chunks = 1176 blocks; 256 threads; M=64, N=96, K-chunk=352, BK=32.
__global__ __launch_bounds__(256) void kGemm1(
    const _Float16* __restrict__ descF, const _Float16* __restrict__ w1f,
    _Float16* __restrict__ pacc) {
  __shared__ _Float16 Ab[2][64 * 32];   // [row*32 + c*8]
  __shared__ _Float16 Bb[2][96 * 32];   // [n*32 + c*8]
  const int t = threadIdx.x;
  const int wv = t >> 6, lane = t & 63, quad = lane >> 4, lr = lane & 15;
  const int mt = blockIdx.x / 6, ck = blockIdx.x % 6;
  const long mblk = (long)mt * 64;

  const long agbase = (mblk + (t >> 2)) * 2112 + ck * 352 + (t & 3) * 8;
  const long bg0 = (long)(t >> 2) * 2112 + ck * 352 + (t & 3) * 8;
  const long bg1 = (long)((256 + t) >> 2) * 2112 + ck * 352 + (t & 3) * 8;
  const int wslot = (t >> 6) * 512;     // wave-uniform LDS base (halves)

  floatx4 acc[6];
#pragma unroll
  for (int j = 0; j < 6; ++j) acc[j] = {0.f, 0.f, 0.f, 0.f};

  gld16(descF + agbase, &Ab[0][wslot]);
  gld16(w1f + bg0, &Bb[0][wslot]);
  if (t < 128) gld16(w1f + bg1, &Bb[0][2048 + wslot]);

  int buf = 0;
  for (int kt = 0; kt < 11; ++kt) {
    __syncthreads();
    if (kt < 10) {
      int off = (kt + 1) * 32;
      gld16(descF + agbase + off, &Ab[buf ^ 1][wslot]);
      gld16(w1f + bg0 + off, &Bb[buf ^ 1][wslot]);
      if (t < 128) gld16(w1f + bg1 + off, &Bb[buf ^ 1][2048 + wslot]);
    }
    half8 af = *(const half8*)(&Ab[buf][(wv * 16 + lr) * 32 + quad * 8]);
#pragma unroll
    for (int j = 0; j < 6; ++j) {
      half8 bf = *(const half8*)(&Bb[buf][(j * 16 + lr) * 32 + quad * 8]);
      acc[j] = __builtin_amdgcn_mfma_f32_16x16x32_f16(af, bf, acc[j], 0, 0, 0);
    }
    buf ^= 1;
  }

  _Float16* pp = pacc + (long)(ck * 196 + mt) * 6144;
#pragma unroll
  for (int j = 0; j < 6; ++j)
#pragma unroll
    for (int r = 0; r < 4; ++r)
      pp[(wv * 16 + quad * 4 + r) * 96 + j * 16 + lr] = (_Float16)acc[j][r];
}

// ---------------- kGemm2 v2: reduce(6 pacc)+BN+ReLU -> y tile -> GEMM2 -> softmax ------
// grid = 392 blocks x 256 threads; 32 rows per block; waves = 2(row-half) x 2(col-half).
__global__ __launch_bounds__(256) void kGemm2(
    const _Float16* __restrict__ pacc,
    const float* __restrict__ gamma, const float* __restrict__ beta,
    const float* __restrict__ mean, const float* __restrict__ var,
    const _Float16* __restrict__ w2f, const _Float16* __restrict__ w3f,
    const float* __restrict__ b2, const float* __restrict__ b3,
    _Float16* __restrict__ wtg) {
  __shared__ __align__(16) char smem[24576];
  _Float16* ytF = (_Float16*)smem;        // [0, 6656): 32*104 fp16 (dead after MFMA loop)
  float* wal = (float*)smem;              // [0, 12288): 32*96 f32 (after ytF dead)
  float* wbl = wal + 3072;                // [12288, 24576)
  __shared__ float invv[96], biasv[96];

  const int t = threadIdx.x;
  const int wv = t >> 6, lane = t & 63, quad = lane >> 4, lr = lane & 15;
  const int wr = wv & 1, wc = wv >> 1;
  const long mblk = (long)blockIdx.x * 32;

  if (t < 96) {
    float iv = gamma[t] * rsqrtf(var[t] + 1e-5f);
    invv[t] = iv; biasv[t] = beta[t] - mean[t] * iv;
  }
  __syncthreads();

  // stage: sum 6 split-K slices + BN + ReLU -> ytF [32][104]; 768 quads / 256 threads
#pragma unroll
  for (int i = 0; i < 3; ++i) {
    int q = t + i * 256;                  // 0..767
    int m = q / 24, nq = (q - m * 24) * 4;
    long gbase = (mblk + m) * 96 + nq;
    float s0 = 0.f, s1 = 0.f, s2 = 0.f, s3 = 0.f;
#pragma unroll
    for (int ck = 0; ck < 6; ++ck) {
      half4 v = *(const half4*)(pacc + (long)ck * 1204224 + gbase);
      s0 += (float)v.x; s1 += (float)v.y; s2 += (float)v.z; s3 += (float)v.w;
    }
    half4 o;
    o.x = (_Float16)fmaxf(s0 * invv[nq + 0] + biasv[nq + 0], 0.f);
    o.y = (_Float16)fmaxf(s1 * invv[nq + 1] + biasv[nq + 1], 0.f);
    o.z = (_Float16)fmaxf(s2 * invv[nq + 2] + biasv[nq + 2], 0.f);
    o.w = (_Float16)fmaxf(s3 * invv[nq + 3] + biasv[nq + 3], 0.f);
    *(half4*)(ytF + m * 104 + nq) = o;
  }
  __syncthreads();

  floatx4 aa[3], ab[3];
#pragma unroll
  for (int j = 0; j < 3; ++j) { aa[j] = {0.f,0.f,0.f,0.f}; ab[j] = {0.f,0.f,0.f,0.f}; }
#pragma unroll
  for (int ks = 0; ks < 3; ++ks) {
    half8 af = *(const half8*)(ytF + (wr * 16 + lr) * 104 + ks * 32 + quad * 8);
#pragma unroll
    for (int j = 0; j < 3; ++j) {
      int n = (wc * 3 + j) * 16 + lr;
      int wo = n * 96 + ks * 32 + quad * 8;
      half8 b2v = *(const half8*)(w2f + wo);
      half8 b3v = *(const half8*)(w3f + wo);
      aa[j] = __builtin_amdgcn_mfma_f32_16x16x32_f16(af, b2v, aa[j], 0, 0, 0);
      ab[j] = __builtin_amdgcn_mfma_f32_16x16x32_f16(af, b3v, ab[j], 0, 0, 0);
    }
  }
  __syncthreads();   // ytF dead; smem becomes wal/wbl

#pragma unroll
  for (int j = 0; j < 3; ++j) {
    int n = (wc * 3 + j) * 16 + lr;
    float bb2 = b2[n], bb3 = b3[n];
#pragma unroll
    for (int r = 0; r < 4; ++r) {
      int m = wr * 16 + quad * 4 + r;
      wal[m * 96 + n] = aa[j][r] + bb2;
      wbl[m * 96 + n] = ab[j][r] + bb3;
    }
  }
  __syncthreads();

  // softmax: 32 rows x 64 (g,ns) units = 2048 / 256 threads
#pragma unroll
  for (int it = 0; it < 8; ++it) {
    int u = t + it * 256;
    int m = u >> 6, rest = u & 63;
    int g = rest >> 2, ns = rest & 3;
    int ns1 = ns >> 1, ns2 = ns & 1;
    float la[3], lb[3];
#pragma unroll
    for (int k = 0; k < 3; ++k) {
      la[k] = wal[m * 96 + (g * 3 + k) * 2 + ns1];
      lb[k] = wbl[m * 96 + (g * 3 + k) * 2 + ns2];
    }
    float lg[9], mx = -1e30f;
#pragma unroll
    for (int k1 = 0; k1 < 3; ++k1)
#pragma unroll
      for (int k2 = 0; k2 < 3; ++k2) {
        float v = la[k1] * lb[k2];
        lg[k1 * 3 + k2] = v;
        mx = v > mx ? v : mx;
      }
    float s = 0.f;
#pragma unroll
    for (int k = 0; k < 9; ++k) { lg[k] = __expf(lg[k] - mx); s += lg[k]; }
    float sc = 1.f / (9.f * s);
    _Float16* dst = wtg + (mblk + m) * 576 + g * 36 + ns * 9;
#pragma unroll
    for (int k = 0; k < 9; ++k) dst[k] = (_Float16)(lg[k] * sc);
  }
}

// ---------------- kApply: x + wt -> out; branch-free fill ----------
// block = (b, h', wh(2), g(16)): 7168 blocks, 256 threads; 16 channels, 28 w-positions.
__global__ __launch_bounds__(256) void kApply(const float* __restrict__ x,
                                              const _Float16* __restrict__ wt,
                                              float* __restrict__ out) {
  int bid = blockIdx.x;
  int g = bid & 15;
  int wh = (bid >> 4) & 1;
  int h = (bid >> 5) % 56;
  int b = bid / 1792;
  int wbase = wh * 28, cbase = g * 16;

  __shared__ _Float16 xr[9 * 16 * 30];       // [(k2*3+k1)*480 + cl*30 + wc]
  __shared__ __align__(16) float wtb[28 * 36]; // [p*36 + (k1*3+k2)*4 + ns]
  __shared__ float ob[32 * 57];              // [(cl*2+ns1)*57 + p*2+ns2]

  int t = threadIdx.x;

  // fill xr: 144 rows x 30 cols; clamped unconditional loads + selects (no branches)
  {
    int wc = t & 31;
    int r0 = t >> 5;                    // 0..7
    int wr = wbase + wc - 1;
    int wrc = min(max(wr, 0), 55);
    bool cok = (wc < 30) & ((unsigned)wr < 56u);
    const long xb0 = ((long)b * 256 + cbase) * 3136;
    float vals[18];
#pragma unroll
    for (int i = 0; i < 18; ++i) {
      int row = r0 + i * 8;             // 0..143
      int kk = row >> 4, cl = row & 15;
      int k2 = (kk >= 6) ? 2 : (kk >= 3 ? 1 : 0);
      int k1 = kk - 3 * k2;
      int t2 = k2 * 56 + h;
      int q3 = (t2 * 683) >> 11;        // t2/3
      int gr = q3 + k1 - 1;
      int grc = min(max(gr, 0), 55);
      float v = x[xb0 + (long)cl * 3136 + (long)grc * 56 + wrc];
      vals[i] = (cok & ((unsigned)gr < 56u)) ? v : 0.f;
    }
#pragma unroll
    for (int i = 0; i < 18; ++i) {
      int row = r0 + i * 8;
      if (wc < 30) xr[row * 30 + wc] = (_Float16)vals[i];
    }
  }
  // wt -> wtb via half4 loads: unit t<252 = (p 0..27, j 0..8); row segment is 36
  // contiguous halves wt[(m0+p)*576 + g*36 + u], u = ns*9+kk; transpose in regs.
  {
    long m0 = ((long)(b * 56 + h)) * 56 + wbase;
    if (t < 252) {
      int p = t / 9, j = t - p * 9;
      half4 v = *(const half4*)(wt + (m0 + p) * 576 + g * 36 + j * 4);
#pragma unroll
      for (int e = 0; e < 4; ++e) {
        int u = j * 4 + e;              // 0..35
        int ns = (u * 57) >> 9;         // u/9 (exact for u<36)
        int kk = u - ns * 9;
        wtb[p * 36 + kk * 4 + ns] = (float)v[e];
      }
    }
  }
  __syncthreads();

  // compute: thread owns (cl, p); 4 ns accumulators; float4 weight reads
  {
    int j2r[3];
#pragma unroll
    for (int k2 = 0; k2 < 3; ++k2) j2r[k2] = (k2 * 56 + h) % 3;
#pragma unroll
    for (int i = 0; i < 2; ++i) {
      int idx = i * 256 + t;
      int cl = idx & 15;
      int p = idx >> 4;                 // 0..31
      if (p < 28) {
        float a0 = 0.f, a1 = 0.f, a2 = 0.f, a3 = 0.f;
#pragma unroll
        for (int k1 = 0; k1 < 3; ++k1)
#pragma unroll
          for (int k2 = 0; k2 < 3; ++k2) {
            float xv = (float)xr[(k2 * 3 + k1) * 480 + cl * 30 + p + j2r[k2]];
            float4 wv = *(const float4*)&wtb[p * 36 + (k1 * 3 + k2) * 4];
            a0 += xv * wv.x; a1 += xv * wv.y; a2 += xv * wv.z; a3 += xv * wv.w;
          }
        int ob0 = cl * 114 + p * 2;
        ob[ob0] = a0;
        ob[ob0 + 1] = a1;
        ob[ob0 + 57] = a2;
        ob[ob0 + 58] = a3;
      }
    }
  }
  __syncthreads();

  // writeout: 32 rows x 56 cols, coalesced
  {
    int wo = t & 63;
    int r0 = t >> 6;                    // 0..3
    const long obase = (((long)b * 256 + cbase) * 112 + 2 * h) * 112 + wh * 56;
#pragma unroll
    for (int i = 0; i < 8; ++i) {
      int row = r0 + i * 4;             // 0..31
      if (wo < 56) {
        int cli = row >> 1, n1 = row & 1;
        out[obase + cli * 12544 + n1 * 112 + wo] = ob[row * 57 + wo];
      }
    }
  }
}

extern "C" void kernel_launch(void* const* d_in, const int* in_sizes, int n_in,
                              void* d_out, int out_size, void* d_ws, size_t ws_size,
                              hipStream_t stream) {
  const float* x = (const float*)d_in[0];
  const float* w1 = (const float*)d_in[1];
  const float* gamma = (const float*)d_in[2];
  const float* beta = (const float*)d_in[3];
  const float* mean = (const float*)d_in[4];
  const float* var = (const float*)d_in[5];
  const float* w2 = (const float*)d_in[6];
  const float* b2 = (const float*)d_in[7];
  const float* w3 = (const float*)d_in[8];
  const float* b3 = (const float*)d_in[9];
  float* out = (float*)d_out;

  // workspace layout (bytes), total ~82 MB:
  //   w1f fp16:   [0, 405504)
  //   w2f fp16:   [405504, 423936)
  //   w3f fp16:   [423936, 442368)
  //   wtg fp16:   [442368, 14893056)
  //   descF fp16: [14893056, 67878912)
  //   pacc fp16:  [67878912, 82329600)   (6 split-K slices)
  _Float16* w1f = (_Float16*)d_ws;
  _Float16* w2f = w1f + 202752;
  _Float16* w3f = w2f + 9216;
  _Float16* wtg = (_Float16*)((char*)d_ws + 442368);
  _Float16* descF = (_Float16*)((char*)d_ws + 14893056);
  _Float16* pacc = (_Float16*)((char*)d_ws + 67878912);

  hipLaunchKernelGGL(kDescC, dim3(4448), dim3(256), 0, stream,
                     x, w1, w2, w3, descF, w1f, w2f, w3f);
  hipLaunchKernelGGL(kGemm1, dim3(1176), dim3(256), 0, stream, descF, w1f, pacc);
  hipLaunchKernelGGL(kGemm2, dim3(392), dim3(256), 0, stream,
                     pacc, gamma, beta, mean, var, w2f, w3f, b2, b3, wtg);
  hipLaunchKernelGGL(kApply, dim3(7168), dim3(256), 0, stream, x, wtg, out);
}